// Round 1
// baseline (8779.409 us; speedup 1.0000x reference)
//
#include <hip/hip_runtime.h>
#include <math.h>

// Problem constants
constexpr int Bn   = 32;
constexpr int Sn   = 256;
constexpr int Dn   = 512;
constexpr int Hn   = 8;
constexpr int DKn  = 64;
constexpr int Fn   = 2048;
constexpr int Ln   = 6;
constexpr int FEATn= 9;
constexpr int BSn  = Bn * Sn;          // 8192 rows

// ---------------------------------------------------------------------------
// Embedding: x = (tgt*mask)@w_f2h + b_f2h + pos_emb + emb_time + emb_gender + emb_race
// one thread per (bs, d) element
// ---------------------------------------------------------------------------
__global__ __launch_bounds__(256)
void k_embed(const float* __restrict__ tgt, const float* __restrict__ mask,
             const float* __restrict__ w_f2h, const float* __restrict__ b_f2h,
             const int* __restrict__ timei, const int* __restrict__ gender,
             const int* __restrict__ race,
             const float* __restrict__ emb_t, const float* __restrict__ emb_g,
             const float* __restrict__ emb_r, float* __restrict__ x)
{
    int idx = blockIdx.x * 256 + threadIdx.x;   // over BSn*Dn
    int d  = idx & (Dn - 1);
    int bs = idx >> 9;                           // /Dn
    int b  = bs / Sn;
    int s  = bs & (Sn - 1);
    const float* tg = tgt  + (size_t)bs * FEATn;
    const float* mk = mask + (size_t)bs * FEATn;
    float acc = b_f2h[d];
    #pragma unroll
    for (int f = 0; f < FEATn; ++f) acc += tg[f] * mk[f] * w_f2h[f * Dn + d];
    // sinusoidal positional embedding: phase = s / 1e4^(d/Dn)
    float phase = (float)s * expf(-((float)d / (float)Dn) * 9.210340372f); // ln(1e4)
    acc += (d & 1) ? cosf(phase) : sinf(phase);
    acc += emb_t[(size_t)timei[bs] * Dn + d];
    acc += emb_g[(size_t)gender[b] * Dn + d];
    acc += emb_r[(size_t)race[b]   * Dn + d];
    x[idx] = acc;
}

// ---------------------------------------------------------------------------
// Tiled fp32 GEMM: C[M,N] = A[M,K] @ W + bias (+R) (ReLU opt)
// HEADED: W is [H, K, 64] per-head blocks; since BN==64==DK each n-tile is one head.
// 64x64 tile, BK=16, 256 threads, 4x4 per-thread microtile.
// ---------------------------------------------------------------------------
template<bool HEADED, bool RELU, bool RESID>
__global__ __launch_bounds__(256)
void k_gemm(const float* __restrict__ A, const float* __restrict__ W,
            const float* __restrict__ bias, const float* __restrict__ R,
            float* __restrict__ C, int M, int N, int K)
{
    __shared__ __align__(16) float As[16][64];   // [k][m]
    __shared__ __align__(16) float Bs[16][64];   // [k][n]
    const int t  = threadIdx.x;
    const int tx = t & 15, ty = t >> 4;
    const int m0 = blockIdx.y * 64;
    const int n0 = blockIdx.x * 64;

    const int am = t >> 2;          // 0..63
    const int ak = (t & 3) << 2;    // 0,4,8,12
    const int bk = t >> 4;          // 0..15
    const int bn = (t & 15) << 2;   // 0..60

    const float* Ap = A + (size_t)(m0 + am) * K + ak;
    const int ldb   = HEADED ? 64 : N;
    const float* Bp = HEADED ? (W + (size_t)(n0 >> 6) * K * 64 + (size_t)bk * 64 + bn)
                             : (W + (size_t)bk * N + n0 + bn);

    float acc[4][4] = {};
    for (int kt = 0; kt < K; kt += 16) {
        float4 a4 = *(const float4*)Ap; Ap += 16;
        float4 b4 = *(const float4*)Bp; Bp += (size_t)16 * ldb;
        As[ak + 0][am] = a4.x; As[ak + 1][am] = a4.y;
        As[ak + 2][am] = a4.z; As[ak + 3][am] = a4.w;
        *(float4*)&Bs[bk][bn] = b4;
        __syncthreads();
        #pragma unroll
        for (int kk = 0; kk < 16; ++kk) {
            float4 av = *(const float4*)&As[kk][ty << 2];
            float4 bv = *(const float4*)&Bs[kk][tx << 2];
            acc[0][0] += av.x * bv.x; acc[0][1] += av.x * bv.y;
            acc[0][2] += av.x * bv.z; acc[0][3] += av.x * bv.w;
            acc[1][0] += av.y * bv.x; acc[1][1] += av.y * bv.y;
            acc[1][2] += av.y * bv.z; acc[1][3] += av.y * bv.w;
            acc[2][0] += av.z * bv.x; acc[2][1] += av.z * bv.y;
            acc[2][2] += av.z * bv.z; acc[2][3] += av.z * bv.w;
            acc[3][0] += av.w * bv.x; acc[3][1] += av.w * bv.y;
            acc[3][2] += av.w * bv.z; acc[3][3] += av.w * bv.w;
        }
        __syncthreads();
    }

    const int gm = m0 + (ty << 2);
    const int gn = n0 + (tx << 2);
    float4 bia = *(const float4*)(bias + gn);
    #pragma unroll
    for (int i = 0; i < 4; ++i) {
        float4 cv;
        cv.x = acc[i][0] + bia.x; cv.y = acc[i][1] + bia.y;
        cv.z = acc[i][2] + bia.z; cv.w = acc[i][3] + bia.w;
        if (RESID) {
            float4 r = *(const float4*)(R + (size_t)(gm + i) * N + gn);
            cv.x += r.x; cv.y += r.y; cv.z += r.z; cv.w += r.w;
        }
        if (RELU) {
            cv.x = fmaxf(cv.x, 0.f); cv.y = fmaxf(cv.y, 0.f);
            cv.z = fmaxf(cv.z, 0.f); cv.w = fmaxf(cv.w, 0.f);
        }
        *(float4*)(C + (size_t)(gm + i) * N + gn) = cv;
    }
}

// ---------------------------------------------------------------------------
// Attention: q,k,v and out all in [B, S, H*DK] layout (head h at col h*64).
// Block = (b, h, q-tile of 16). softmax over S keys, scale 1/8.
// ---------------------------------------------------------------------------
constexpr int QT = 16;
__global__ __launch_bounds__(256)
void k_attn(const float* __restrict__ q, const float* __restrict__ k,
            const float* __restrict__ v, float* __restrict__ ocat)
{
    __shared__ float qs[QT][DKn];        // 4 KB
    __shared__ float st[QT][Sn];         // 16 KB
    __shared__ float part[4][QT][DKn];   // 16 KB
    const int t   = threadIdx.x;
    const int blk = blockIdx.x;              // Bn*Hn*(Sn/QT)
    const int qt  = blk & (Sn / QT - 1);
    const int bh  = blk / (Sn / QT);
    const int h   = bh & (Hn - 1), b = bh / Hn;
    const int q0  = qt * QT;
    const size_t base = (size_t)b * Sn * Dn + (size_t)h * DKn; // row (b,s) col h*64

    // load Q tile (16x64)
    #pragma unroll
    for (int i = 0; i < QT * DKn / 256; ++i) {
        int idx = i * 256 + t;
        int qq = idx >> 6, dd = idx & 63;
        qs[qq][dd] = q[base + (size_t)(q0 + qq) * Dn + dd];
    }
    __syncthreads();

    // scores: thread t owns key j=t, computes 16 dots
    float sc[QT];
    #pragma unroll
    for (int i = 0; i < QT; ++i) sc[i] = 0.f;
    const float* kr = k + base + (size_t)t * Dn;
    for (int d = 0; d < DKn; ++d) {
        float kv = kr[d];
        #pragma unroll
        for (int i = 0; i < QT; ++i) sc[i] += qs[i][d] * kv;
    }
    #pragma unroll
    for (int i = 0; i < QT; ++i) st[i][t] = sc[i] * 0.125f;  // 1/sqrt(64)
    __syncthreads();

    // softmax: thread (r = t>>4 row, c = t&15) handles 16 strided elems; 16-lane xor reduce
    {
        int r = t >> 4, c = t & 15;
        float vv[16];
        float mx = -1e30f;
        #pragma unroll
        for (int i = 0; i < 16; ++i) { vv[i] = st[r][c + 16 * i]; mx = fmaxf(mx, vv[i]); }
        #pragma unroll
        for (int off = 8; off; off >>= 1) mx = fmaxf(mx, __shfl_xor(mx, off));
        float sum = 0.f;
        #pragma unroll
        for (int i = 0; i < 16; ++i) { vv[i] = __expf(vv[i] - mx); sum += vv[i]; }
        #pragma unroll
        for (int off = 8; off; off >>= 1) sum += __shfl_xor(sum, off);
        float rn = 1.f / sum;
        #pragma unroll
        for (int i = 0; i < 16; ++i) st[r][c + 16 * i] = vv[i] * rn;
    }
    __syncthreads();

    // AV: group g = t>>6 covers keys [g*64, g*64+64); dv = t&63 output dim
    {
        int g = t >> 6, dv = t & 63;
        float acc[QT];
        #pragma unroll
        for (int i = 0; i < QT; ++i) acc[i] = 0.f;
        const float* vr = v + base + dv;
        for (int s = 0; s < 64; ++s) {
            int sg = g * 64 + s;
            float vv = vr[(size_t)sg * Dn];
            #pragma unroll
            for (int i = 0; i < QT; ++i) acc[i] += st[i][sg] * vv;
        }
        #pragma unroll
        for (int i = 0; i < QT; ++i) part[g][i][dv] = acc[i];
    }
    __syncthreads();

    // reduce partials & write out (already concat-head layout)
    #pragma unroll
    for (int i = 0; i < 4; ++i) {
        int idx = i * 256 + t;     // over QT*DKn = 1024
        int qq = idx >> 6, dv = idx & 63;
        float r = part[0][qq][dv] + part[1][qq][dv] + part[2][qq][dv] + part[3][qq][dv];
        ocat[base + (size_t)(q0 + qq) * Dn + dv] = r;
    }
}

// ---------------------------------------------------------------------------
// LayerNorm over D=512, block per row, 256 threads (2 elems each)
// ---------------------------------------------------------------------------
__global__ __launch_bounds__(256)
void k_ln(const float* __restrict__ y, const float* __restrict__ g,
          const float* __restrict__ be, float* __restrict__ xo)
{
    __shared__ float r1[4], r2[4];
    const int row = blockIdx.x;
    const int t = threadIdx.x;
    const float* yr = y + (size_t)row * Dn;
    float v0 = yr[t], v1 = yr[t + 256];
    float s1 = v0 + v1, s2 = v0 * v0 + v1 * v1;
    #pragma unroll
    for (int off = 32; off; off >>= 1) { s1 += __shfl_xor(s1, off); s2 += __shfl_xor(s2, off); }
    if ((t & 63) == 0) { r1[t >> 6] = s1; r2[t >> 6] = s2; }
    __syncthreads();
    float S1 = r1[0] + r1[1] + r1[2] + r1[3];
    float S2 = r2[0] + r2[1] + r2[2] + r2[3];
    float mean = S1 * (1.f / Dn);
    float var  = S2 * (1.f / Dn) - mean * mean;
    float isd  = rsqrtf(var + 1e-5f);
    xo[(size_t)row * Dn + t]       = (v0 - mean) * isd * g[t]       + be[t];
    xo[(size_t)row * Dn + t + 256] = (v1 - mean) * isd * g[t + 256] + be[t + 256];
}

// ---------------------------------------------------------------------------
// Final: out0 = sigmoid(x@w_out+b_out), out1 = float(time), out2 = sigmoid(x@w_m+b_m)
// block per row; row of x staged in LDS; 18 dot products + 1 copy
// ---------------------------------------------------------------------------
__global__ __launch_bounds__(256)
void k_final(const float* __restrict__ x, const float* __restrict__ w_out,
             const float* __restrict__ b_out, const float* __restrict__ w_m,
             const float* __restrict__ b_m, const int* __restrict__ timei,
             float* __restrict__ out)
{
    __shared__ float xr[Dn];
    const int row = blockIdx.x;
    const int t = threadIdx.x;
    xr[t]       = x[(size_t)row * Dn + t];
    xr[t + 256] = x[(size_t)row * Dn + t + 256];
    __syncthreads();
    if (t < 2 * FEATn) {
        int j = t % FEATn;
        bool m = t >= FEATn;
        const float* w = m ? w_m : w_out;
        float acc = m ? b_m[j] : b_out[j];
        for (int d = 0; d < Dn; ++d) acc += xr[d] * w[d * FEATn + j];
        float sg = 1.f / (1.f + expf(-acc));
        size_t off = m ? ((size_t)BSn * FEATn + BSn) : 0;
        out[off + (size_t)row * FEATn + j] = sg;
    }
    if (t == 2 * FEATn) out[(size_t)BSn * FEATn + row] = (float)timei[row];
}

// ---------------------------------------------------------------------------
extern "C" void kernel_launch(void* const* d_in, const int* in_sizes, int n_in,
                              void* d_out, int out_size, void* d_ws, size_t ws_size,
                              hipStream_t stream)
{
    const float* tgt    = (const float*)d_in[0];
    const float* memory = (const float*)d_in[1];
    const int*   timei  = (const int*)  d_in[2];
    const int*   gender = (const int*)  d_in[3];
    const int*   race   = (const int*)  d_in[4];
    const float* maskp  = (const float*)d_in[5];
    const float* w_f2h  = (const float*)d_in[6];
    const float* b_f2h  = (const float*)d_in[7];
    const float* emb_t  = (const float*)d_in[8];
    const float* emb_g  = (const float*)d_in[9];
    const float* emb_r  = (const float*)d_in[10];
    const float* wq1 = (const float*)d_in[11]; const float* bq1 = (const float*)d_in[12];
    const float* wk1 = (const float*)d_in[13]; const float* bk1 = (const float*)d_in[14];
    const float* wv1 = (const float*)d_in[15]; const float* bv1 = (const float*)d_in[16];
    const float* wo1 = (const float*)d_in[17]; const float* bo1 = (const float*)d_in[18];
    const float* g1  = (const float*)d_in[19]; const float* be1 = (const float*)d_in[20];
    const float* wq2 = (const float*)d_in[21]; const float* bq2 = (const float*)d_in[22];
    const float* wk2 = (const float*)d_in[23]; const float* bk2 = (const float*)d_in[24];
    const float* wv2 = (const float*)d_in[25]; const float* bv2 = (const float*)d_in[26];
    const float* wo2 = (const float*)d_in[27]; const float* bo2 = (const float*)d_in[28];
    const float* g2  = (const float*)d_in[29]; const float* be2 = (const float*)d_in[30];
    const float* w1f = (const float*)d_in[31]; const float* b1f = (const float*)d_in[32];
    const float* w2f = (const float*)d_in[33]; const float* b2f = (const float*)d_in[34];
    const float* gfp = (const float*)d_in[35]; const float* bff = (const float*)d_in[36];
    const float* w_out = (const float*)d_in[37]; const float* b_out = (const float*)d_in[38];
    const float* w_m   = (const float*)d_in[39]; const float* b_m   = (const float*)d_in[40];
    float* out = (float*)d_out;

    // workspace: x, b1..b5 (each BSn*Dn floats); FFN hidden overlays b1..b4
    constexpr size_t N1 = (size_t)BSn * Dn;
    float* x  = (float*)d_ws;
    float* b1 = x  + N1;
    float* b2 = b1 + N1;
    float* b3 = b2 + N1;
    float* b4 = b3 + N1;
    float* b5 = b4 + N1;
    float* h1 = b1;   // BSn*Fn floats == 4*N1, spans b1..b4

    dim3 blk(256);
    k_embed<<<dim3((BSn * Dn) / 256), blk, 0, stream>>>(
        tgt, maskp, w_f2h, b_f2h, timei, gender, race, emb_t, emb_g, emb_r, x);

    dim3 gP(Dn / 64, BSn / 64);    // N=512 GEMMs
    dim3 gF1(Fn / 64, BSn / 64);   // N=2048 GEMM
    dim3 gA(Bn * Hn * (Sn / QT));  // attention blocks
    const size_t WSL = (size_t)Hn * Dn * DKn;  // per-layer qkv/wo weight stride (262144)

    for (int l = 0; l < Ln; ++l) {
        // ---- self-attention block ----
        k_gemm<true , false, false><<<gP, blk, 0, stream>>>(x, wq1 + l * WSL, bq1 + l * Hn * DKn, nullptr, b1, BSn, Dn, Dn);
        k_gemm<true , false, false><<<gP, blk, 0, stream>>>(x, wk1 + l * WSL, bk1 + l * Hn * DKn, nullptr, b2, BSn, Dn, Dn);
        k_gemm<true , false, false><<<gP, blk, 0, stream>>>(x, wv1 + l * WSL, bv1 + l * Hn * DKn, nullptr, b3, BSn, Dn, Dn);
        k_attn<<<gA, blk, 0, stream>>>(b1, b2, b3, b4);
        k_gemm<false, false, true ><<<gP, blk, 0, stream>>>(b4, wo1 + l * WSL, bo1 + l * Dn, x, b5, BSn, Dn, Dn);
        k_ln<<<dim3(BSn), blk, 0, stream>>>(b5, g1 + l * Dn, be1 + l * Dn, x);
        // ---- cross block: q,k from memory; v from x ----
        k_gemm<true , false, false><<<gP, blk, 0, stream>>>(memory, wq2 + l * WSL, bq2 + l * Hn * DKn, nullptr, b1, BSn, Dn, Dn);
        k_gemm<true , false, false><<<gP, blk, 0, stream>>>(memory, wk2 + l * WSL, bk2 + l * Hn * DKn, nullptr, b2, BSn, Dn, Dn);
        k_gemm<true , false, false><<<gP, blk, 0, stream>>>(x,      wv2 + l * WSL, bv2 + l * Hn * DKn, nullptr, b3, BSn, Dn, Dn);
        k_attn<<<gA, blk, 0, stream>>>(b1, b2, b3, b4);
        k_gemm<false, false, true ><<<gP, blk, 0, stream>>>(b4, wo2 + l * WSL, bo2 + l * Dn, x, b5, BSn, Dn, Dn);
        k_ln<<<dim3(BSn), blk, 0, stream>>>(b5, g2 + l * Dn, be2 + l * Dn, x);
        // ---- feed-forward ----
        k_gemm<false, true , false><<<gF1, blk, 0, stream>>>(x,  w1f + (size_t)l * Dn * Fn, b1f + l * Fn, nullptr, h1, BSn, Fn, Dn);
        k_gemm<false, false, true ><<<gP , blk, 0, stream>>>(h1, w2f + (size_t)l * Fn * Dn, b2f + l * Dn, x, b5, BSn, Dn, Fn);
        k_ln<<<dim3(BSn), blk, 0, stream>>>(b5, gfp + l * Dn, bff + l * Dn, x);
    }

    k_final<<<dim3(BSn), blk, 0, stream>>>(x, w_out, b_out, w_m, b_m, timei, out);
}

// Round 2
// 3374.360 us; speedup vs baseline: 2.6018x; 2.6018x over previous
//
#include <hip/hip_runtime.h>
#include <hip/hip_bf16.h>
#include <math.h>

// Problem constants
constexpr int Bn   = 32;
constexpr int Sn   = 256;
constexpr int Dn   = 512;
constexpr int Hn   = 8;
constexpr int DKn  = 64;
constexpr int Fn   = 2048;
constexpr int Ln   = 6;
constexpr int FEATn= 9;
constexpr int BSn  = Bn * Sn;          // 8192 rows

typedef __hip_bfloat16 bf16;
typedef __attribute__((ext_vector_type(8))) short short8;
typedef __attribute__((ext_vector_type(4))) float f32x4;

// global->LDS async copy, 16B per lane, LDS dest = wave-uniform base + lane*16
#define GLOAD_LDS16(gp, lp)                                                   \
    __builtin_amdgcn_global_load_lds(                                         \
        (const __attribute__((address_space(1))) void*)(gp),                  \
        (__attribute__((address_space(3))) void*)(lp), 16, 0, 0)

// ---------------------------------------------------------------------------
// Embedding: x = (tgt*mask)@w_f2h + b_f2h + pos_emb + emb_time/gender/race
// ---------------------------------------------------------------------------
__global__ __launch_bounds__(256)
void k_embed(const float* __restrict__ tgt, const float* __restrict__ mask,
             const float* __restrict__ w_f2h, const float* __restrict__ b_f2h,
             const int* __restrict__ timei, const int* __restrict__ gender,
             const int* __restrict__ race,
             const float* __restrict__ emb_t, const float* __restrict__ emb_g,
             const float* __restrict__ emb_r, bf16* __restrict__ x)
{
    int idx = blockIdx.x * 256 + threadIdx.x;   // over BSn*Dn
    int d  = idx & (Dn - 1);
    int bs = idx >> 9;                           // /Dn
    int b  = bs / Sn;
    int s  = bs & (Sn - 1);
    const float* tg = tgt  + (size_t)bs * FEATn;
    const float* mk = mask + (size_t)bs * FEATn;
    float acc = b_f2h[d];
    #pragma unroll
    for (int f = 0; f < FEATn; ++f) acc += tg[f] * mk[f] * w_f2h[f * Dn + d];
    float phase = (float)s * expf(-((float)d / (float)Dn) * 9.210340372f); // ln(1e4)
    acc += (d & 1) ? cosf(phase) : sinf(phase);
    acc += emb_t[(size_t)timei[bs] * Dn + d];
    acc += emb_g[(size_t)gender[b] * Dn + d];
    acc += emb_r[(size_t)race[b]   * Dn + d];
    x[idx] = __float2bfloat16(acc);
}

// ---------------------------------------------------------------------------
// fp32 -> bf16 elementwise convert
// ---------------------------------------------------------------------------
__global__ __launch_bounds__(256)
void k_cvt(const float* __restrict__ in, bf16* __restrict__ out)
{
    int i = blockIdx.x * 256 + threadIdx.x;
    out[i] = __float2bfloat16(in[i]);
}

// ---------------------------------------------------------------------------
// Transpose + convert: in fp32 [B][R][C]  ->  out bf16 [B][C][R]
// 32x32 LDS tile, padded stride 33 (no bank conflicts)
// ---------------------------------------------------------------------------
__global__ __launch_bounds__(256)
void k_tcvt(const float* __restrict__ in, bf16* __restrict__ out, int R, int C)
{
    __shared__ float ts[32][33];
    const int t  = threadIdx.x;
    const int tx = t & 31, ty = t >> 5;       // 8 rows per pass
    const int r0 = blockIdx.y * 32, c0 = blockIdx.x * 32;
    const size_t zo = (size_t)blockIdx.z * R * C;
    #pragma unroll
    for (int i = 0; i < 4; ++i)
        ts[ty + 8 * i][tx] = in[zo + (size_t)(r0 + ty + 8 * i) * C + c0 + tx];
    __syncthreads();
    #pragma unroll
    for (int i = 0; i < 4; ++i)
        out[zo + (size_t)(c0 + ty + 8 * i) * R + r0 + tx] =
            __float2bfloat16(ts[tx][ty + 8 * i]);
}

// ---------------------------------------------------------------------------
// bf16 MFMA GEMM (m97 recipe): C[M,N] = A[M,K] @ Bt[N,K]^T + bias (+R)(ReLU)
// 128x128 tile, BK=32, 256 threads = 4 waves, each wave 64x64 (4x4 MFMA tiles)
// blockIdx.z selects (A,W,bias,C) triple -> fused QKV launches.
// ---------------------------------------------------------------------------
template<bool RELU, bool RESID>
__global__ __launch_bounds__(256)
void k_gemm_bf(const bf16* __restrict__ A0, const bf16* __restrict__ A1,
               const bf16* __restrict__ A2,
               const bf16* __restrict__ W0, const bf16* __restrict__ W1,
               const bf16* __restrict__ W2,
               const float* __restrict__ bi0, const float* __restrict__ bi1,
               const float* __restrict__ bi2,
               const bf16* __restrict__ R,
               bf16* __restrict__ C0, bf16* __restrict__ C1, bf16* __restrict__ C2,
               int M, int N, int K)
{
    const int z = blockIdx.z;
    const short* A   = (const short*)(z == 0 ? A0 : (z == 1 ? A1 : A2));
    const short* W   = (const short*)(z == 0 ? W0 : (z == 1 ? W1 : W2));
    const float* bia = (z == 0 ? bi0 : (z == 1 ? bi1 : bi2));
    bf16*        C   = (z == 0 ? C0 : (z == 1 ? C1 : C2));

    __shared__ __align__(16) short As[128 * 32];  // [row][k] 64B rows
    __shared__ __align__(16) short Bs[128 * 32];

    const int t    = threadIdx.x;
    const int w    = t >> 6, lane = t & 63;
    const int m0   = blockIdx.y * 128, n0 = blockIdx.x * 128;
    const int l16  = lane & 15, quad = lane >> 4;
    const int wm   = (w & 1) * 64, wn = (w >> 1) * 64;

    // staging: chunk c (16B) covers row c>>2, k-part (c&3)*8; wave w owns
    // chunks [w*128, w*128+128) in two wave-wide calls of 64 chunks each.
    const int c1 = w * 128 + lane;
    const int c2 = c1 + 64;
    const short* Ag1 = A + (size_t)(m0 + (c1 >> 2)) * K + (c1 & 3) * 8;
    const short* Ag2 = A + (size_t)(m0 + (c2 >> 2)) * K + (c2 & 3) * 8;
    const short* Bg1 = W + (size_t)(n0 + (c1 >> 2)) * K + (c1 & 3) * 8;
    const short* Bg2 = W + (size_t)(n0 + (c2 >> 2)) * K + (c2 & 3) * 8;
    short* Al = As + w * 1024;   // w*2048 bytes
    short* Bl = Bs + w * 1024;

    f32x4 acc[4][4] = {};

    for (int k0 = 0; k0 < K; k0 += 32) {
        GLOAD_LDS16(Ag1, Al);
        GLOAD_LDS16(Ag2, Al + 512);
        GLOAD_LDS16(Bg1, Bl);
        GLOAD_LDS16(Bg2, Bl + 512);
        Ag1 += 32; Ag2 += 32; Bg1 += 32; Bg2 += 32;
        __syncthreads();

        short8 af[4], bf[4];
        #pragma unroll
        for (int mi = 0; mi < 4; ++mi)
            af[mi] = *(const short8*)(As + (wm + mi * 16 + l16) * 32 + quad * 8);
        #pragma unroll
        for (int ni = 0; ni < 4; ++ni)
            bf[ni] = *(const short8*)(Bs + (wn + ni * 16 + l16) * 32 + quad * 8);
        #pragma unroll
        for (int mi = 0; mi < 4; ++mi)
            #pragma unroll
            for (int ni = 0; ni < 4; ++ni)
                acc[mi][ni] = __builtin_amdgcn_mfma_f32_16x16x32_bf16(
                    af[mi], bf[ni], acc[mi][ni], 0, 0, 0);
        __syncthreads();
    }

    // epilogue: D row = quad*4 + r, col = l16 (verified m89/m91 layout)
    #pragma unroll
    for (int ni = 0; ni < 4; ++ni) {
        const int col = n0 + wn + ni * 16 + l16;
        const float bb = bia[col];
        #pragma unroll
        for (int mi = 0; mi < 4; ++mi) {
            #pragma unroll
            for (int r = 0; r < 4; ++r) {
                const int row = m0 + wm + mi * 16 + quad * 4 + r;
                float v = acc[mi][ni][r] + bb;
                if (RESID) v += __bfloat162float(R[(size_t)row * N + col]);
                if (RELU)  v = fmaxf(v, 0.f);
                C[(size_t)row * N + col] = __float2bfloat16(v);
            }
        }
    }
}

// ---------------------------------------------------------------------------
// Attention (bf16 in/out): q,k,v,out in [B, S, H*DK] layout
// ---------------------------------------------------------------------------
constexpr int QT = 16;
__global__ __launch_bounds__(256)
void k_attn(const bf16* __restrict__ q, const bf16* __restrict__ k,
            const bf16* __restrict__ v, bf16* __restrict__ ocat)
{
    __shared__ float qs[QT][DKn];        // 4 KB
    __shared__ float st[QT][Sn];         // 16 KB
    __shared__ float part[4][QT][DKn];   // 16 KB
    const int t   = threadIdx.x;
    const int blk = blockIdx.x;
    const int qt  = blk & (Sn / QT - 1);
    const int bh  = blk / (Sn / QT);
    const int h   = bh & (Hn - 1), b = bh / Hn;
    const int q0  = qt * QT;
    const size_t base = (size_t)b * Sn * Dn + (size_t)h * DKn;

    #pragma unroll
    for (int i = 0; i < QT * DKn / 256; ++i) {
        int idx = i * 256 + t;
        int qq = idx >> 6, dd = idx & 63;
        qs[qq][dd] = __bfloat162float(q[base + (size_t)(q0 + qq) * Dn + dd]);
    }
    __syncthreads();

    float sc[QT];
    #pragma unroll
    for (int i = 0; i < QT; ++i) sc[i] = 0.f;
    const bf16* kr = k + base + (size_t)t * Dn;
    for (int d = 0; d < DKn; ++d) {
        float kv = __bfloat162float(kr[d]);
        #pragma unroll
        for (int i = 0; i < QT; ++i) sc[i] += qs[i][d] * kv;
    }
    #pragma unroll
    for (int i = 0; i < QT; ++i) st[i][t] = sc[i] * 0.125f;
    __syncthreads();

    {
        int r = t >> 4, c = t & 15;
        float vv[16];
        float mx = -1e30f;
        #pragma unroll
        for (int i = 0; i < 16; ++i) { vv[i] = st[r][c + 16 * i]; mx = fmaxf(mx, vv[i]); }
        #pragma unroll
        for (int off = 8; off; off >>= 1) mx = fmaxf(mx, __shfl_xor(mx, off));
        float sum = 0.f;
        #pragma unroll
        for (int i = 0; i < 16; ++i) { vv[i] = __expf(vv[i] - mx); sum += vv[i]; }
        #pragma unroll
        for (int off = 8; off; off >>= 1) sum += __shfl_xor(sum, off);
        float rn = 1.f / sum;
        #pragma unroll
        for (int i = 0; i < 16; ++i) st[r][c + 16 * i] = vv[i] * rn;
    }
    __syncthreads();

    {
        int g = t >> 6, dv = t & 63;
        float acc[QT];
        #pragma unroll
        for (int i = 0; i < QT; ++i) acc[i] = 0.f;
        const bf16* vr = v + base + dv;
        for (int s = 0; s < 64; ++s) {
            int sg = g * 64 + s;
            float vv = __bfloat162float(vr[(size_t)sg * Dn]);
            #pragma unroll
            for (int i = 0; i < QT; ++i) acc[i] += st[i][sg] * vv;
        }
        #pragma unroll
        for (int i = 0; i < QT; ++i) part[g][i][dv] = acc[i];
    }
    __syncthreads();

    #pragma unroll
    for (int i = 0; i < 4; ++i) {
        int idx = i * 256 + t;     // over QT*DKn = 1024
        int qq = idx >> 6, dv = idx & 63;
        float r = part[0][qq][dv] + part[1][qq][dv] + part[2][qq][dv] + part[3][qq][dv];
        ocat[base + (size_t)(q0 + qq) * Dn + dv] = __float2bfloat16(r);
    }
}

// ---------------------------------------------------------------------------
// LayerNorm over D=512, block per row (bf16 in/out; in-place safe)
// ---------------------------------------------------------------------------
__global__ __launch_bounds__(256)
void k_ln(const bf16* __restrict__ y, const float* __restrict__ g,
          const float* __restrict__ be, bf16* __restrict__ xo)
{
    __shared__ float r1[4], r2[4];
    const int row = blockIdx.x;
    const int t = threadIdx.x;
    const bf16* yr = y + (size_t)row * Dn;
    float v0 = __bfloat162float(yr[t]), v1 = __bfloat162float(yr[t + 256]);
    float s1 = v0 + v1, s2 = v0 * v0 + v1 * v1;
    #pragma unroll
    for (int off = 32; off; off >>= 1) { s1 += __shfl_xor(s1, off); s2 += __shfl_xor(s2, off); }
    if ((t & 63) == 0) { r1[t >> 6] = s1; r2[t >> 6] = s2; }
    __syncthreads();
    float S1 = r1[0] + r1[1] + r1[2] + r1[3];
    float S2 = r2[0] + r2[1] + r2[2] + r2[3];
    float mean = S1 * (1.f / Dn);
    float var  = S2 * (1.f / Dn) - mean * mean;
    float isd  = rsqrtf(var + 1e-5f);
    xo[(size_t)row * Dn + t]       = __float2bfloat16((v0 - mean) * isd * g[t]       + be[t]);
    xo[(size_t)row * Dn + t + 256] = __float2bfloat16((v1 - mean) * isd * g[t + 256] + be[t + 256]);
}

// ---------------------------------------------------------------------------
// Final: sigmoid(x@w_out+b_out), float(time), sigmoid(x@w_m+b_m)
// ---------------------------------------------------------------------------
__global__ __launch_bounds__(256)
void k_final(const bf16* __restrict__ x, const float* __restrict__ w_out,
             const float* __restrict__ b_out, const float* __restrict__ w_m,
             const float* __restrict__ b_m, const int* __restrict__ timei,
             float* __restrict__ out)
{
    __shared__ float xr[Dn];
    const int row = blockIdx.x;
    const int t = threadIdx.x;
    xr[t]       = __bfloat162float(x[(size_t)row * Dn + t]);
    xr[t + 256] = __bfloat162float(x[(size_t)row * Dn + t + 256]);
    __syncthreads();
    if (t < 2 * FEATn) {
        int j = t % FEATn;
        bool m = t >= FEATn;
        const float* w = m ? w_m : w_out;
        float acc = m ? b_m[j] : b_out[j];
        for (int d = 0; d < Dn; ++d) acc += xr[d] * w[d * FEATn + j];
        float sg = 1.f / (1.f + expf(-acc));
        size_t off = m ? ((size_t)BSn * FEATn + BSn) : 0;
        out[off + (size_t)row * FEATn + j] = sg;
    }
    if (t == 2 * FEATn) out[(size_t)BSn * FEATn + row] = (float)timei[row];
}

// ---------------------------------------------------------------------------
extern "C" void kernel_launch(void* const* d_in, const int* in_sizes, int n_in,
                              void* d_out, int out_size, void* d_ws, size_t ws_size,
                              hipStream_t stream)
{
    const float* tgt    = (const float*)d_in[0];
    const float* memory = (const float*)d_in[1];
    const int*   timei  = (const int*)  d_in[2];
    const int*   gender = (const int*)  d_in[3];
    const int*   race   = (const int*)  d_in[4];
    const float* maskp  = (const float*)d_in[5];
    const float* w_f2h  = (const float*)d_in[6];
    const float* b_f2h  = (const float*)d_in[7];
    const float* emb_t  = (const float*)d_in[8];
    const float* emb_g  = (const float*)d_in[9];
    const float* emb_r  = (const float*)d_in[10];
    const float* wq1 = (const float*)d_in[11]; const float* bq1 = (const float*)d_in[12];
    const float* wk1 = (const float*)d_in[13]; const float* bk1 = (const float*)d_in[14];
    const float* wv1 = (const float*)d_in[15]; const float* bv1 = (const float*)d_in[16];
    const float* wo1 = (const float*)d_in[17]; const float* bo1 = (const float*)d_in[18];
    const float* g1  = (const float*)d_in[19]; const float* be1 = (const float*)d_in[20];
    const float* wq2 = (const float*)d_in[21]; const float* bq2 = (const float*)d_in[22];
    const float* wk2 = (const float*)d_in[23]; const float* bk2 = (const float*)d_in[24];
    const float* wv2 = (const float*)d_in[25]; const float* bv2 = (const float*)d_in[26];
    const float* wo2 = (const float*)d_in[27]; const float* bo2 = (const float*)d_in[28];
    const float* g2  = (const float*)d_in[29]; const float* be2 = (const float*)d_in[30];
    const float* w1f = (const float*)d_in[31]; const float* b1f = (const float*)d_in[32];
    const float* w2f = (const float*)d_in[33]; const float* b2f = (const float*)d_in[34];
    const float* gfp = (const float*)d_in[35]; const float* bff = (const float*)d_in[36];
    const float* w_out = (const float*)d_in[37]; const float* b_out = (const float*)d_in[38];
    const float* w_m   = (const float*)d_in[39]; const float* b_m   = (const float*)d_in[40];
    float* out = (float*)d_out;

    // ---- workspace layout (bf16 elems), total 100,663,296 bytes ----
    constexpr size_t WH  = 1572864;            // headed / wo per-array (48*512*64 or 6*512*512)
    constexpr size_t WF  = 6291456;            // w1f / w2f per-array
    constexpr size_t NA  = (size_t)BSn * Dn;   // 4,194,304 activation elems
    bf16* wsb   = (bf16*)d_ws;
    bf16* wq1t  = wsb;
    bf16* wk1t  = wq1t + WH;
    bf16* wv1t  = wk1t + WH;
    bf16* wo1t  = wv1t + WH;
    bf16* wq2t  = wo1t + WH;
    bf16* wk2t  = wq2t + WH;
    bf16* wv2t  = wk2t + WH;
    bf16* wo2t  = wv2t + WH;
    bf16* w1ft  = wo2t + WH;
    bf16* w2ft  = w1ft + WF;
    bf16* memb  = w2ft + WF;
    bf16* x     = memb + NA;
    bf16* b1    = x  + NA;
    bf16* b2    = b1 + NA;
    bf16* b3    = b2 + NA;
    bf16* b4    = b3 + NA;
    bf16* h1    = b1;          // [8192][2048] spans b1..b4 exactly

    dim3 blk(256);

    // ---- weight transpose+convert: [*][R][C] fp32 -> [*][C][R] bf16 ----
    k_tcvt<<<dim3( 2, 16, 48), blk, 0, stream>>>(wq1, wq1t, 512, 64);
    k_tcvt<<<dim3( 2, 16, 48), blk, 0, stream>>>(wk1, wk1t, 512, 64);
    k_tcvt<<<dim3( 2, 16, 48), blk, 0, stream>>>(wv1, wv1t, 512, 64);
    k_tcvt<<<dim3(16, 16,  6), blk, 0, stream>>>(wo1, wo1t, 512, 512);
    k_tcvt<<<dim3( 2, 16, 48), blk, 0, stream>>>(wq2, wq2t, 512, 64);
    k_tcvt<<<dim3( 2, 16, 48), blk, 0, stream>>>(wk2, wk2t, 512, 64);
    k_tcvt<<<dim3( 2, 16, 48), blk, 0, stream>>>(wv2, wv2t, 512, 64);
    k_tcvt<<<dim3(16, 16,  6), blk, 0, stream>>>(wo2, wo2t, 512, 512);
    k_tcvt<<<dim3(64, 16,  6), blk, 0, stream>>>(w1f, w1ft, 512, 2048);
    k_tcvt<<<dim3(16, 64,  6), blk, 0, stream>>>(w2f, w2ft, 2048, 512);
    k_cvt <<<dim3(NA / 256), blk, 0, stream>>>(memory, memb);

    k_embed<<<dim3((BSn * Dn) / 256), blk, 0, stream>>>(
        tgt, maskp, w_f2h, b_f2h, timei, gender, race, emb_t, emb_g, emb_r, x);

    dim3 gP (Dn / 128, BSn / 128, 1);   // 4 x 64       projection / wo / ffn2
    dim3 gP3(Dn / 128, BSn / 128, 3);   // fused qkv
    dim3 gF (Fn / 128, BSn / 128, 1);   // 16 x 64      ffn1
    dim3 gA (Bn * Hn * (Sn / QT));
    constexpr size_t WSL = 262144;      // per-layer stride, headed/wo (512*512)
    constexpr size_t WFL = 1048576;     // per-layer stride, ffn (512*2048)

    for (int l = 0; l < Ln; ++l) {
        // ---- self-attention ----
        k_gemm_bf<false, false><<<gP3, blk, 0, stream>>>(
            x, x, x,
            wq1t + l * WSL, wk1t + l * WSL, wv1t + l * WSL,
            bq1 + l * Dn, bk1 + l * Dn, bv1 + l * Dn,
            nullptr, b1, b2, b3, BSn, Dn, Dn);
        k_attn<<<gA, blk, 0, stream>>>(b1, b2, b3, b4);
        k_gemm_bf<false, true ><<<gP, blk, 0, stream>>>(
            b4, b4, b4, wo1t + l * WSL, wo1t + l * WSL, wo1t + l * WSL,
            bo1 + l * Dn, bo1 + l * Dn, bo1 + l * Dn,
            x, x, x, x, BSn, Dn, Dn);
        k_ln<<<dim3(BSn), blk, 0, stream>>>(x, g1 + l * Dn, be1 + l * Dn, x);
        // ---- cross block: q,k from memory; v from x ----
        k_gemm_bf<false, false><<<gP3, blk, 0, stream>>>(
            memb, memb, x,
            wq2t + l * WSL, wk2t + l * WSL, wv2t + l * WSL,
            bq2 + l * Dn, bk2 + l * Dn, bv2 + l * Dn,
            nullptr, b1, b2, b3, BSn, Dn, Dn);
        k_attn<<<gA, blk, 0, stream>>>(b1, b2, b3, b4);
        k_gemm_bf<false, true ><<<gP, blk, 0, stream>>>(
            b4, b4, b4, wo2t + l * WSL, wo2t + l * WSL, wo2t + l * WSL,
            bo2 + l * Dn, bo2 + l * Dn, bo2 + l * Dn,
            x, x, x, x, BSn, Dn, Dn);
        k_ln<<<dim3(BSn), blk, 0, stream>>>(x, g2 + l * Dn, be2 + l * Dn, x);
        // ---- feed-forward ----
        k_gemm_bf<true , false><<<gF, blk, 0, stream>>>(
            x, x, x, w1ft + l * WFL, w1ft + l * WFL, w1ft + l * WFL,
            b1f + l * Fn, b1f + l * Fn, b1f + l * Fn,
            nullptr, h1, h1, h1, BSn, Fn, Dn);
        k_gemm_bf<false, true ><<<gP, blk, 0, stream>>>(
            h1, h1, h1, w2ft + l * WFL, w2ft + l * WFL, w2ft + l * WFL,
            b2f + l * Dn, b2f + l * Dn, b2f + l * Dn,
            x, x, x, x, BSn, Dn, Fn);
        k_ln<<<dim3(BSn), blk, 0, stream>>>(x, gfp + l * Dn, bff + l * Dn, x);
    }

    k_final<<<dim3(BSn), blk, 0, stream>>>(x, w_out, b_out, w_m, b_m, timei, out);
}

// Round 3
// 1863.160 us; speedup vs baseline: 4.7121x; 1.8111x over previous
//
#include <hip/hip_runtime.h>
#include <hip/hip_bf16.h>
#include <math.h>

// Problem constants
constexpr int Bn   = 32;
constexpr int Sn   = 256;
constexpr int Dn   = 512;
constexpr int Hn   = 8;
constexpr int DKn  = 64;
constexpr int Fn   = 2048;
constexpr int Ln   = 6;
constexpr int FEATn= 9;
constexpr int BSn  = Bn * Sn;          // 8192 rows

typedef __hip_bfloat16 bf16;
typedef __attribute__((ext_vector_type(8))) short short8;
typedef __attribute__((ext_vector_type(4))) short short4v;
typedef __attribute__((ext_vector_type(4))) float f32x4;

// global->LDS async copy, 16B per lane, LDS dest = wave-uniform base + lane*16
#define GLOAD_LDS16(gp, lp)                                                   \
    __builtin_amdgcn_global_load_lds(                                         \
        (const __attribute__((address_space(1))) void*)(gp),                  \
        (__attribute__((address_space(3))) void*)(lp), 16, 0, 0)

__device__ __forceinline__ short f2bs(float f) {
    __hip_bfloat16 h = __float2bfloat16(f);
    return *reinterpret_cast<short*>(&h);
}

// ---------------------------------------------------------------------------
// Embedding: x = (tgt*mask)@w_f2h + b_f2h + pos_emb + emb_time/gender/race
// ---------------------------------------------------------------------------
__global__ __launch_bounds__(256)
void k_embed(const float* __restrict__ tgt, const float* __restrict__ mask,
             const float* __restrict__ w_f2h, const float* __restrict__ b_f2h,
             const int* __restrict__ timei, const int* __restrict__ gender,
             const int* __restrict__ race,
             const float* __restrict__ emb_t, const float* __restrict__ emb_g,
             const float* __restrict__ emb_r, bf16* __restrict__ x)
{
    int idx = blockIdx.x * 256 + threadIdx.x;   // over BSn*Dn
    int d  = idx & (Dn - 1);
    int bs = idx >> 9;                           // /Dn
    int b  = bs / Sn;
    int s  = bs & (Sn - 1);
    const float* tg = tgt  + (size_t)bs * FEATn;
    const float* mk = mask + (size_t)bs * FEATn;
    float acc = b_f2h[d];
    #pragma unroll
    for (int f = 0; f < FEATn; ++f) acc += tg[f] * mk[f] * w_f2h[f * Dn + d];
    float phase = (float)s * expf(-((float)d / (float)Dn) * 9.210340372f); // ln(1e4)
    acc += (d & 1) ? cosf(phase) : sinf(phase);
    acc += emb_t[(size_t)timei[bs] * Dn + d];
    acc += emb_g[(size_t)gender[b] * Dn + d];
    acc += emb_r[(size_t)race[b]   * Dn + d];
    x[idx] = __float2bfloat16(acc);
}

// ---------------------------------------------------------------------------
// fp32 -> bf16 elementwise convert
// ---------------------------------------------------------------------------
__global__ __launch_bounds__(256)
void k_cvt(const float* __restrict__ in, bf16* __restrict__ out)
{
    int i = blockIdx.x * 256 + threadIdx.x;
    out[i] = __float2bfloat16(in[i]);
}

// ---------------------------------------------------------------------------
// Transpose + convert: in fp32 [B][R][C]  ->  out bf16 [B][C][R]
// ---------------------------------------------------------------------------
__global__ __launch_bounds__(256)
void k_tcvt(const float* __restrict__ in, bf16* __restrict__ out, int R, int C)
{
    __shared__ float ts[32][33];
    const int t  = threadIdx.x;
    const int tx = t & 31, ty = t >> 5;       // 8 rows per pass
    const int r0 = blockIdx.y * 32, c0 = blockIdx.x * 32;
    const size_t zo = (size_t)blockIdx.z * R * C;
    #pragma unroll
    for (int i = 0; i < 4; ++i)
        ts[ty + 8 * i][tx] = in[zo + (size_t)(r0 + ty + 8 * i) * C + c0 + tx];
    __syncthreads();
    #pragma unroll
    for (int i = 0; i < 4; ++i)
        out[zo + (size_t)(c0 + ty + 8 * i) * R + r0 + tx] =
            __float2bfloat16(ts[tx][ty + 8 * i]);
}

// ---------------------------------------------------------------------------
// bf16 MFMA GEMM: C[M,N] = A[M,K] @ Bt[N,K]^T + bias (+R)(ReLU)
// 128x128 tile, BK=32, 4 waves, wave 64x64.  blockIdx.z picks (A,W,bias,C).
// TRANSV && z==2: operand-swapped MFMA -> writes C^T as [N][M] (for attention V).
// ---------------------------------------------------------------------------
template<bool RELU, bool RESID, bool TRANSV = false>
__global__ __launch_bounds__(256)
void k_gemm_bf(const bf16* __restrict__ A0, const bf16* __restrict__ A1,
               const bf16* __restrict__ A2,
               const bf16* __restrict__ W0, const bf16* __restrict__ W1,
               const bf16* __restrict__ W2,
               const float* __restrict__ bi0, const float* __restrict__ bi1,
               const float* __restrict__ bi2,
               const bf16* __restrict__ R,
               bf16* __restrict__ C0, bf16* __restrict__ C1, bf16* __restrict__ C2,
               int M, int N, int K)
{
    const int z = blockIdx.z;
    const short* A   = (const short*)(z == 0 ? A0 : (z == 1 ? A1 : A2));
    const short* W   = (const short*)(z == 0 ? W0 : (z == 1 ? W1 : W2));
    const float* bia = (z == 0 ? bi0 : (z == 1 ? bi1 : bi2));
    bf16*        C   = (z == 0 ? C0 : (z == 1 ? C1 : C2));

    __shared__ __align__(16) short As[128 * 32];  // [row][k] 64B rows
    __shared__ __align__(16) short Bs[128 * 32];

    const int t    = threadIdx.x;
    const int w    = t >> 6, lane = t & 63;
    const int m0   = blockIdx.y * 128, n0 = blockIdx.x * 128;
    const int l16  = lane & 15, quad = lane >> 4;
    const int wm   = (w & 1) * 64, wn = (w >> 1) * 64;

    const int c1 = w * 128 + lane;
    const int c2 = c1 + 64;
    const short* Ag1 = A + (size_t)(m0 + (c1 >> 2)) * K + (c1 & 3) * 8;
    const short* Ag2 = A + (size_t)(m0 + (c2 >> 2)) * K + (c2 & 3) * 8;
    const short* Bg1 = W + (size_t)(n0 + (c1 >> 2)) * K + (c1 & 3) * 8;
    const short* Bg2 = W + (size_t)(n0 + (c2 >> 2)) * K + (c2 & 3) * 8;
    short* Al = As + w * 1024;
    short* Bl = Bs + w * 1024;

    f32x4 acc[4][4] = {};
    const bool tv = TRANSV && (z == 2);

    for (int k0 = 0; k0 < K; k0 += 32) {
        GLOAD_LDS16(Ag1, Al);
        GLOAD_LDS16(Ag2, Al + 512);
        GLOAD_LDS16(Bg1, Bl);
        GLOAD_LDS16(Bg2, Bl + 512);
        Ag1 += 32; Ag2 += 32; Bg1 += 32; Bg2 += 32;
        __syncthreads();

        short8 af[4], bf[4];
        #pragma unroll
        for (int mi = 0; mi < 4; ++mi)
            af[mi] = *(const short8*)(As + (wm + mi * 16 + l16) * 32 + quad * 8);
        #pragma unroll
        for (int ni = 0; ni < 4; ++ni)
            bf[ni] = *(const short8*)(Bs + (wn + ni * 16 + l16) * 32 + quad * 8);
        if (tv) {
            #pragma unroll
            for (int mi = 0; mi < 4; ++mi)
                #pragma unroll
                for (int ni = 0; ni < 4; ++ni)
                    acc[mi][ni] = __builtin_amdgcn_mfma_f32_16x16x32_bf16(
                        bf[ni], af[mi], acc[mi][ni], 0, 0, 0);
        } else {
            #pragma unroll
            for (int mi = 0; mi < 4; ++mi)
                #pragma unroll
                for (int ni = 0; ni < 4; ++ni)
                    acc[mi][ni] = __builtin_amdgcn_mfma_f32_16x16x32_bf16(
                        af[mi], bf[ni], acc[mi][ni], 0, 0, 0);
        }
        __syncthreads();
    }

    if (tv) {
        // D[m=W-row][n=token]: row = wn-index, col = token; write C^T [N][M]
        #pragma unroll
        for (int ni = 0; ni < 4; ++ni) {
            #pragma unroll
            for (int r = 0; r < 4; ++r) {
                const int wrow = n0 + wn + ni * 16 + quad * 4 + r;
                const float bb = bia[wrow];
                #pragma unroll
                for (int mi = 0; mi < 4; ++mi) {
                    const int tok = m0 + wm + mi * 16 + l16;
                    C[(size_t)wrow * M + tok] = __float2bfloat16(acc[mi][ni][r] + bb);
                }
            }
        }
    } else {
        #pragma unroll
        for (int ni = 0; ni < 4; ++ni) {
            const int col = n0 + wn + ni * 16 + l16;
            const float bb = bia[col];
            #pragma unroll
            for (int mi = 0; mi < 4; ++mi) {
                #pragma unroll
                for (int r = 0; r < 4; ++r) {
                    const int row = m0 + wm + mi * 16 + quad * 4 + r;
                    float v = acc[mi][ni][r] + bb;
                    if (RESID) v += __bfloat162float(R[(size_t)row * N + col]);
                    if (RELU)  v = fmaxf(v, 0.f);
                    C[(size_t)row * N + col] = __float2bfloat16(v);
                }
            }
        }
    }
}

// ---------------------------------------------------------------------------
// MFMA attention. q,k in [B,S,H*DK]; vT in [H*DK][B*S] (from TRANSV v-proj);
// out in [B,S,H*DK].  Block = (b,h,64-query tile), 4 waves x (16q x 256k).
// S^T = K@Q^T via operand swap -> softmax over keys = in-lane + shfl 16/32.
// P round-trips LDS (C-layout -> A-layout), keys packed 4-wide (b64 writes).
// K/Vt staged via global_load_lds with XOR chunk swizzle (global-side).
// ---------------------------------------------------------------------------
__global__ __launch_bounds__(256)
void k_attn_mfma(const bf16* __restrict__ q, const bf16* __restrict__ k,
                 const bf16* __restrict__ vT, bf16* __restrict__ ocat)
{
    __shared__ __align__(16) short smem[33280];      // 66560 B
    short* Vst = smem;            // [64 dv][256 key], 16B chunks XOR-swizzled
    short* Ks  = smem + 16384;    // [256 key][64 dk], 16B chunks XOR-swizzled
    short* Ps  = smem + 16384;    // [64 q][264] bf16, overlays Ks (after barrier)

    const int t = threadIdx.x, w = t >> 6, lane = t & 63;
    const int l16 = lane & 15, quad = lane >> 4;
    const int qt = blockIdx.x & 3;
    const int h  = (blockIdx.x >> 2) & 7;
    const int b  = blockIdx.x >> 5;
    const int q0 = qt * 64;

    const short* kg = (const short*)k  + (size_t)b * Sn * Dn + h * DKn;
    const short* qg = (const short*)q  + (size_t)b * Sn * Dn + h * DKn;
    const short* vg = (const short*)vT + (size_t)h * DKn * BSn + b * Sn;

    // ---- stage K (2048 chunks) and Vt (2048 chunks), 8 calls each per wave ----
    #pragma unroll
    for (int i = 0; i < 8; ++i) {
        const int c   = w * 512 + i * 64 + lane;
        const int key = c >> 3, cgk = (c & 7) ^ (key & 7);
        GLOAD_LDS16(kg + (size_t)key * Dn + cgk * 8, Ks + (w * 512 + i * 64) * 8);
        const int dv = c >> 5, cgv = (c & 31) ^ (dv & 7);
        GLOAD_LDS16(vg + (size_t)dv * BSn + cgv * 8, Vst + (w * 512 + i * 64) * 8);
    }

    // ---- Q B-fragments straight from global (wave's 16 queries) ----
    const short* qp = qg + (size_t)(q0 + w * 16 + l16) * Dn + quad * 8;
    short8 bq0 = *(const short8*)(qp);
    short8 bq1 = *(const short8*)(qp + 32);
    __syncthreads();   // staging drain (vmcnt(0) before barrier)

    // ---- S^T = K @ Q^T : acc[mi]: key = mi*16+quad*4+r, query = l16 ----
    f32x4 accs[16];
    #pragma unroll
    for (int mi = 0; mi < 16; ++mi) accs[mi] = f32x4{0.f, 0.f, 0.f, 0.f};
    #pragma unroll
    for (int mi = 0; mi < 16; ++mi) {
        const int key = mi * 16 + l16;
        const int r0s = (quad     ^ (key & 7)) * 8;       // k0=0 chunk
        const int r1s = ((quad+4) ^ (key & 7)) * 8;       // k0=32 chunk
        short8 af0 = *(const short8*)(Ks + key * 64 + r0s);
        short8 af1 = *(const short8*)(Ks + key * 64 + r1s);
        accs[mi] = __builtin_amdgcn_mfma_f32_16x16x32_bf16(af0, bq0, accs[mi], 0, 0, 0);
        accs[mi] = __builtin_amdgcn_mfma_f32_16x16x32_bf16(af1, bq1, accs[mi], 0, 0, 0);
    }

    // ---- softmax over keys (per query l16): in-lane 64 + shfl over quads ----
    float mx = -1e30f;
    #pragma unroll
    for (int mi = 0; mi < 16; ++mi)
        #pragma unroll
        for (int r = 0; r < 4; ++r) mx = fmaxf(mx, accs[mi][r]);
    mx = fmaxf(mx, __shfl_xor(mx, 16));
    mx = fmaxf(mx, __shfl_xor(mx, 32));
    float sum = 0.f;
    #pragma unroll
    for (int mi = 0; mi < 16; ++mi)
        #pragma unroll
        for (int r = 0; r < 4; ++r) {
            float e = __expf((accs[mi][r] - mx) * 0.125f);   // scale 1/sqrt(64)
            accs[mi][r] = e;
            sum += e;
        }
    sum += __shfl_xor(sum, 16);
    sum += __shfl_xor(sum, 32);
    const float rs = 1.f / sum;

    __syncthreads();   // all K-reads done before P overlays Ks

    // ---- write P [query][key] (bf16, row stride 264), packed 4 keys -> b64 ----
    short* pr = Ps + (w * 16 + l16) * 264;
    #pragma unroll
    for (int mi = 0; mi < 16; ++mi) {
        short4v pk;
        pk.x = f2bs(accs[mi][0] * rs);
        pk.y = f2bs(accs[mi][1] * rs);
        pk.z = f2bs(accs[mi][2] * rs);
        pk.w = f2bs(accs[mi][3] * rs);
        *(short4v*)(pr + mi * 16 + quad * 4) = pk;
    }
    __syncthreads();

    // ---- O = P @ V : A = P (LDS), B = V[k=key][n=dv] = Vst rows ----
    f32x4 acco[4];
    #pragma unroll
    for (int nt = 0; nt < 4; ++nt) acco[nt] = f32x4{0.f, 0.f, 0.f, 0.f};
    #pragma unroll
    for (int k0 = 0; k0 < 8; ++k0) {
        short8 pa = *(const short8*)(pr + k0 * 32 + quad * 8);
        #pragma unroll
        for (int nt = 0; nt < 4; ++nt) {
            const int dv = nt * 16 + l16;
            const int sl = ((4 * k0 + quad) ^ (dv & 7)) * 8;
            short8 vb = *(const short8*)(Vst + dv * 256 + sl);
            acco[nt] = __builtin_amdgcn_mfma_f32_16x16x32_bf16(pa, vb, acco[nt], 0, 0, 0);
        }
    }

    // ---- epilogue: D[m=query][n=dv] ----
    #pragma unroll
    for (int nt = 0; nt < 4; ++nt) {
        #pragma unroll
        for (int r = 0; r < 4; ++r) {
            const int row = b * Sn + q0 + w * 16 + quad * 4 + r;
            const int col = h * DKn + nt * 16 + l16;
            ocat[(size_t)row * Dn + col] = __float2bfloat16(acco[nt][r]);
        }
    }
}

// ---------------------------------------------------------------------------
// LayerNorm over D=512, block per row (bf16 in/out; in-place safe)
// ---------------------------------------------------------------------------
__global__ __launch_bounds__(256)
void k_ln(const bf16* __restrict__ y, const float* __restrict__ g,
          const float* __restrict__ be, bf16* __restrict__ xo)
{
    __shared__ float r1[4], r2[4];
    const int row = blockIdx.x;
    const int t = threadIdx.x;
    const bf16* yr = y + (size_t)row * Dn;
    float v0 = __bfloat162float(yr[t]), v1 = __bfloat162float(yr[t + 256]);
    float s1 = v0 + v1, s2 = v0 * v0 + v1 * v1;
    #pragma unroll
    for (int off = 32; off; off >>= 1) { s1 += __shfl_xor(s1, off); s2 += __shfl_xor(s2, off); }
    if ((t & 63) == 0) { r1[t >> 6] = s1; r2[t >> 6] = s2; }
    __syncthreads();
    float S1 = r1[0] + r1[1] + r1[2] + r1[3];
    float S2 = r2[0] + r2[1] + r2[2] + r2[3];
    float mean = S1 * (1.f / Dn);
    float var  = S2 * (1.f / Dn) - mean * mean;
    float isd  = rsqrtf(var + 1e-5f);
    xo[(size_t)row * Dn + t]       = __float2bfloat16((v0 - mean) * isd * g[t]       + be[t]);
    xo[(size_t)row * Dn + t + 256] = __float2bfloat16((v1 - mean) * isd * g[t + 256] + be[t + 256]);
}

// ---------------------------------------------------------------------------
// Final: sigmoid(x@w_out+b_out), float(time), sigmoid(x@w_m+b_m)
// ---------------------------------------------------------------------------
__global__ __launch_bounds__(256)
void k_final(const bf16* __restrict__ x, const float* __restrict__ w_out,
             const float* __restrict__ b_out, const float* __restrict__ w_m,
             const float* __restrict__ b_m, const int* __restrict__ timei,
             float* __restrict__ out)
{
    __shared__ float xr[Dn];
    const int row = blockIdx.x;
    const int t = threadIdx.x;
    xr[t]       = __bfloat162float(x[(size_t)row * Dn + t]);
    xr[t + 256] = __bfloat162float(x[(size_t)row * Dn + t + 256]);
    __syncthreads();
    if (t < 2 * FEATn) {
        int j = t % FEATn;
        bool m = t >= FEATn;
        const float* w = m ? w_m : w_out;
        float acc = m ? b_m[j] : b_out[j];
        for (int d = 0; d < Dn; ++d) acc += xr[d] * w[d * FEATn + j];
        float sg = 1.f / (1.f + expf(-acc));
        size_t off = m ? ((size_t)BSn * FEATn + BSn) : 0;
        out[off + (size_t)row * FEATn + j] = sg;
    }
    if (t == 2 * FEATn) out[(size_t)BSn * FEATn + row] = (float)timei[row];
}

// ---------------------------------------------------------------------------
extern "C" void kernel_launch(void* const* d_in, const int* in_sizes, int n_in,
                              void* d_out, int out_size, void* d_ws, size_t ws_size,
                              hipStream_t stream)
{
    const float* tgt    = (const float*)d_in[0];
    const float* memory = (const float*)d_in[1];
    const int*   timei  = (const int*)  d_in[2];
    const int*   gender = (const int*)  d_in[3];
    const int*   race   = (const int*)  d_in[4];
    const float* maskp  = (const float*)d_in[5];
    const float* w_f2h  = (const float*)d_in[6];
    const float* b_f2h  = (const float*)d_in[7];
    const float* emb_t  = (const float*)d_in[8];
    const float* emb_g  = (const float*)d_in[9];
    const float* emb_r  = (const float*)d_in[10];
    const float* wq1 = (const float*)d_in[11]; const float* bq1 = (const float*)d_in[12];
    const float* wk1 = (const float*)d_in[13]; const float* bk1 = (const float*)d_in[14];
    const float* wv1 = (const float*)d_in[15]; const float* bv1 = (const float*)d_in[16];
    const float* wo1 = (const float*)d_in[17]; const float* bo1 = (const float*)d_in[18];
    const float* g1  = (const float*)d_in[19]; const float* be1 = (const float*)d_in[20];
    const float* wq2 = (const float*)d_in[21]; const float* bq2 = (const float*)d_in[22];
    const float* wk2 = (const float*)d_in[23]; const float* bk2 = (const float*)d_in[24];
    const float* wv2 = (const float*)d_in[25]; const float* bv2 = (const float*)d_in[26];
    const float* wo2 = (const float*)d_in[27]; const float* bo2 = (const float*)d_in[28];
    const float* g2  = (const float*)d_in[29]; const float* be2 = (const float*)d_in[30];
    const float* w1f = (const float*)d_in[31]; const float* b1f = (const float*)d_in[32];
    const float* w2f = (const float*)d_in[33]; const float* b2f = (const float*)d_in[34];
    const float* gfp = (const float*)d_in[35]; const float* bff = (const float*)d_in[36];
    const float* w_out = (const float*)d_in[37]; const float* b_out = (const float*)d_in[38];
    const float* w_m   = (const float*)d_in[39]; const float* b_m   = (const float*)d_in[40];
    float* out = (float*)d_out;

    // ---- workspace layout (bf16 elems) ----
    constexpr size_t WH  = 1572864;            // headed / wo per-array
    constexpr size_t WF  = 6291456;            // w1f / w2f per-array
    constexpr size_t NA  = (size_t)BSn * Dn;   // activation elems
    bf16* wsb   = (bf16*)d_ws;
    bf16* wq1t  = wsb;
    bf16* wk1t  = wq1t + WH;
    bf16* wv1t  = wk1t + WH;
    bf16* wo1t  = wv1t + WH;
    bf16* wq2t  = wo1t + WH;
    bf16* wk2t  = wq2t + WH;
    bf16* wv2t  = wk2t + WH;
    bf16* wo2t  = wv2t + WH;
    bf16* w1ft  = wo2t + WH;
    bf16* w2ft  = w1ft + WF;
    bf16* memb  = w2ft + WF;
    bf16* x     = memb + NA;
    bf16* b1    = x  + NA;
    bf16* b2    = b1 + NA;
    bf16* b3    = b2 + NA;     // Vt [512][8192] from TRANSV v-proj
    bf16* b4    = b3 + NA;
    bf16* h1    = b1;          // [8192][2048] spans b1..b4

    dim3 blk(256);

    // ---- weight transpose+convert: [*][R][C] fp32 -> [*][C][R] bf16 ----
    k_tcvt<<<dim3( 2, 16, 48), blk, 0, stream>>>(wq1, wq1t, 512, 64);
    k_tcvt<<<dim3( 2, 16, 48), blk, 0, stream>>>(wk1, wk1t, 512, 64);
    k_tcvt<<<dim3( 2, 16, 48), blk, 0, stream>>>(wv1, wv1t, 512, 64);
    k_tcvt<<<dim3(16, 16,  6), blk, 0, stream>>>(wo1, wo1t, 512, 512);
    k_tcvt<<<dim3( 2, 16, 48), blk, 0, stream>>>(wq2, wq2t, 512, 64);
    k_tcvt<<<dim3( 2, 16, 48), blk, 0, stream>>>(wk2, wk2t, 512, 64);
    k_tcvt<<<dim3( 2, 16, 48), blk, 0, stream>>>(wv2, wv2t, 512, 64);
    k_tcvt<<<dim3(16, 16,  6), blk, 0, stream>>>(wo2, wo2t, 512, 512);
    k_tcvt<<<dim3(64, 16,  6), blk, 0, stream>>>(w1f, w1ft, 512, 2048);
    k_tcvt<<<dim3(16, 64,  6), blk, 0, stream>>>(w2f, w2ft, 2048, 512);
    k_cvt <<<dim3(NA / 256), blk, 0, stream>>>(memory, memb);

    k_embed<<<dim3((BSn * Dn) / 256), blk, 0, stream>>>(
        tgt, maskp, w_f2h, b_f2h, timei, gender, race, emb_t, emb_g, emb_r, x);

    dim3 gP (Dn / 128, BSn / 128, 1);
    dim3 gP3(Dn / 128, BSn / 128, 3);
    dim3 gF (Fn / 128, BSn / 128, 1);
    dim3 gA (Bn * Hn * 4);
    constexpr size_t WSL = 262144;
    constexpr size_t WFL = 1048576;

    for (int l = 0; l < Ln; ++l) {
        // ---- self-attention ----
        k_gemm_bf<false, false, true><<<gP3, blk, 0, stream>>>(
            x, x, x,
            wq1t + l * WSL, wk1t + l * WSL, wv1t + l * WSL,
            bq1 + l * Dn, bk1 + l * Dn, bv1 + l * Dn,
            nullptr, b1, b2, b3, BSn, Dn, Dn);
        k_attn_mfma<<<gA, blk, 0, stream>>>(b1, b2, b3, b4);
        k_gemm_bf<false, true ><<<gP, blk, 0, stream>>>(
            b4, b4, b4, wo1t + l * WSL, wo1t + l * WSL, wo1t + l * WSL,
            bo1 + l * Dn, bo1 + l * Dn, bo1 + l * Dn,
            x, x, x, x, BSn, Dn, Dn);
        k_ln<<<dim3(BSn), blk, 0, stream>>>(x, g1 + l * Dn, be1 + l * Dn, x);
        // ---- cross block: q,k from memory; v from x ----
        k_gemm_bf<false, false, true><<<gP3, blk, 0, stream>>>(
            memb, memb, x,
            wq2t + l * WSL, wk2t + l * WSL, wv2t + l * WSL,
            bq2 + l * Dn, bk2 + l * Dn, bv2 + l * Dn,
            nullptr, b1, b2, b3, BSn, Dn, Dn);
        k_attn_mfma<<<gA, blk, 0, stream>>>(b1, b2, b3, b4);
        k_gemm_bf<false, true ><<<gP, blk, 0, stream>>>(
            b4, b4, b4, wo2t + l * WSL, wo2t + l * WSL, wo2t + l * WSL,
            bo2 + l * Dn, bo2 + l * Dn, bo2 + l * Dn,
            x, x, x, x, BSn, Dn, Dn);
        k_ln<<<dim3(BSn), blk, 0, stream>>>(x, g2 + l * Dn, be2 + l * Dn, x);
        // ---- feed-forward ----
        k_gemm_bf<true , false><<<gF, blk, 0, stream>>>(
            x, x, x, w1ft + l * WFL, w1ft + l * WFL, w1ft + l * WFL,
            b1f + l * Fn, b1f + l * Fn, b1f + l * Fn,
            nullptr, h1, h1, h1, BSn, Fn, Dn);
        k_gemm_bf<false, true ><<<gP, blk, 0, stream>>>(
            h1, h1, h1, w2ft + l * WFL, w2ft + l * WFL, w2ft + l * WFL,
            b2f + l * Dn, b2f + l * Dn, b2f + l * Dn,
            x, x, x, x, BSn, Dn, Fn);
        k_ln<<<dim3(BSn), blk, 0, stream>>>(x, gfp + l * Dn, bff + l * Dn, x);
    }

    k_final<<<dim3(BSn), blk, 0, stream>>>(x, w_out, b_out, w_m, b_m, timei, out);
}

// Round 4
// 1744.432 us; speedup vs baseline: 5.0328x; 1.0681x over previous
//
#include <hip/hip_runtime.h>
#include <hip/hip_bf16.h>
#include <math.h>

// Problem constants
constexpr int Bn   = 32;
constexpr int Sn   = 256;
constexpr int Dn   = 512;
constexpr int Hn   = 8;
constexpr int DKn  = 64;
constexpr int Fn   = 2048;
constexpr int Ln   = 6;
constexpr int FEATn= 9;
constexpr int BSn  = Bn * Sn;          // 8192 rows

typedef __hip_bfloat16 bf16;
typedef __attribute__((ext_vector_type(8))) short short8;
typedef __attribute__((ext_vector_type(4))) short short4v;
typedef __attribute__((ext_vector_type(4))) float f32x4;

// global->LDS async copy, 16B per lane, LDS dest = wave-uniform base + lane*16
#define GLOAD_LDS16(gp, lp)                                                   \
    __builtin_amdgcn_global_load_lds(                                         \
        (const __attribute__((address_space(1))) void*)(gp),                  \
        (__attribute__((address_space(3))) void*)(lp), 16, 0, 0)

__device__ __forceinline__ short f2bs(float f) {
    __hip_bfloat16 h = __float2bfloat16(f);
    return *reinterpret_cast<short*>(&h);
}
__device__ __forceinline__ float bs2f(short s) {
    unsigned u = ((unsigned)(unsigned short)s) << 16;
    return *reinterpret_cast<float*>(&u);
}

// ---------------------------------------------------------------------------
// Embedding: x = (tgt*mask)@w_f2h + b_f2h + pos_emb + emb_time/gender/race
// ---------------------------------------------------------------------------
__global__ __launch_bounds__(256)
void k_embed(const float* __restrict__ tgt, const float* __restrict__ mask,
             const float* __restrict__ w_f2h, const float* __restrict__ b_f2h,
             const int* __restrict__ timei, const int* __restrict__ gender,
             const int* __restrict__ race,
             const float* __restrict__ emb_t, const float* __restrict__ emb_g,
             const float* __restrict__ emb_r, bf16* __restrict__ x)
{
    int idx = blockIdx.x * 256 + threadIdx.x;   // over BSn*Dn
    int d  = idx & (Dn - 1);
    int bs = idx >> 9;                           // /Dn
    int b  = bs / Sn;
    int s  = bs & (Sn - 1);
    const float* tg = tgt  + (size_t)bs * FEATn;
    const float* mk = mask + (size_t)bs * FEATn;
    float acc = b_f2h[d];
    #pragma unroll
    for (int f = 0; f < FEATn; ++f) acc += tg[f] * mk[f] * w_f2h[f * Dn + d];
    float phase = (float)s * expf(-((float)d / (float)Dn) * 9.210340372f); // ln(1e4)
    acc += (d & 1) ? cosf(phase) : sinf(phase);
    acc += emb_t[(size_t)timei[bs] * Dn + d];
    acc += emb_g[(size_t)gender[b] * Dn + d];
    acc += emb_r[(size_t)race[b]   * Dn + d];
    x[idx] = __float2bfloat16(acc);
}

// ---------------------------------------------------------------------------
// fp32 -> bf16 elementwise convert
// ---------------------------------------------------------------------------
__global__ __launch_bounds__(256)
void k_cvt(const float* __restrict__ in, bf16* __restrict__ out)
{
    int i = blockIdx.x * 256 + threadIdx.x;
    out[i] = __float2bfloat16(in[i]);
}

// ---------------------------------------------------------------------------
// Transpose + convert: in fp32 [B][R][C] -> out bf16 [B][C][R]
// Batched over up to 6 source/dest pairs: z in [0, 6*ZB); sel = z / ZB.
// ---------------------------------------------------------------------------
__global__ __launch_bounds__(256)
void k_tcvt6(const float* __restrict__ i0, bf16* __restrict__ o0,
             const float* __restrict__ i1, bf16* __restrict__ o1,
             const float* __restrict__ i2, bf16* __restrict__ o2,
             const float* __restrict__ i3, bf16* __restrict__ o3,
             const float* __restrict__ i4, bf16* __restrict__ o4,
             const float* __restrict__ i5, bf16* __restrict__ o5,
             int R, int C, int ZB)
{
    __shared__ float ts[32][33];
    const int sel = blockIdx.z / ZB, zi = blockIdx.z % ZB;
    const float* in  = sel == 0 ? i0 : sel == 1 ? i1 : sel == 2 ? i2
                     : sel == 3 ? i3 : sel == 4 ? i4 : i5;
    bf16*        out = sel == 0 ? o0 : sel == 1 ? o1 : sel == 2 ? o2
                     : sel == 3 ? o3 : sel == 4 ? o4 : o5;
    const int t  = threadIdx.x;
    const int tx = t & 31, ty = t >> 5;       // 8 rows per pass
    const int r0 = blockIdx.y * 32, c0 = blockIdx.x * 32;
    const size_t zo = (size_t)zi * R * C;
    #pragma unroll
    for (int i = 0; i < 4; ++i)
        ts[ty + 8 * i][tx] = in[zo + (size_t)(r0 + ty + 8 * i) * C + c0 + tx];
    __syncthreads();
    #pragma unroll
    for (int i = 0; i < 4; ++i)
        out[zo + (size_t)(c0 + ty + 8 * i) * R + r0 + tx] =
            __float2bfloat16(ts[tx][ty + 8 * i]);
}

// ---------------------------------------------------------------------------
// Prep for k_final2: Wcat bf16 [32][512] = concat(w_out^T, w_m^T, zero-pad),
// bcat fp32 [32] = concat(b_out, b_m, 0)
// ---------------------------------------------------------------------------
__global__ __launch_bounds__(256)
void k_prep_final(const float* __restrict__ w_out, const float* __restrict__ b_out,
                  const float* __restrict__ w_m, const float* __restrict__ b_m,
                  bf16* __restrict__ Wcat, float* __restrict__ bcat)
{
    int idx = blockIdx.x * 256 + threadIdx.x;   // 32*512
    int n = idx >> 9, k = idx & 511;
    float v = 0.f;
    if (n < FEATn)          v = w_out[(size_t)k * FEATn + n];
    else if (n < 2 * FEATn) v = w_m[(size_t)k * FEATn + (n - FEATn)];
    Wcat[idx] = __float2bfloat16(v);
    if (idx < 32) {
        float bv = idx < FEATn ? b_out[idx]
                 : (idx < 2 * FEATn ? b_m[idx - FEATn] : 0.f);
        bcat[idx] = bv;
    }
}

// ---------------------------------------------------------------------------
// bf16 MFMA GEMM: C[M,N] = A[M,K] @ Bt[N,K]^T + bias (+R)(ReLU)
// 128x128 tile, BK=32, 4 waves, wave 64x64.  blockIdx.z picks (A,W,bias,C).
// TRANSV && z==2: operand-swapped MFMA -> writes C^T as [N][M] (for attention V).
// ---------------------------------------------------------------------------
template<bool RELU, bool RESID, bool TRANSV = false>
__global__ __launch_bounds__(256)
void k_gemm_bf(const bf16* __restrict__ A0, const bf16* __restrict__ A1,
               const bf16* __restrict__ A2,
               const bf16* __restrict__ W0, const bf16* __restrict__ W1,
               const bf16* __restrict__ W2,
               const float* __restrict__ bi0, const float* __restrict__ bi1,
               const float* __restrict__ bi2,
               const bf16* __restrict__ R,
               bf16* __restrict__ C0, bf16* __restrict__ C1, bf16* __restrict__ C2,
               int M, int N, int K)
{
    const int z = blockIdx.z;
    const short* A   = (const short*)(z == 0 ? A0 : (z == 1 ? A1 : A2));
    const short* W   = (const short*)(z == 0 ? W0 : (z == 1 ? W1 : W2));
    const float* bia = (z == 0 ? bi0 : (z == 1 ? bi1 : bi2));
    bf16*        C   = (z == 0 ? C0 : (z == 1 ? C1 : C2));

    __shared__ __align__(16) short As[128 * 32];  // [row][k] 64B rows
    __shared__ __align__(16) short Bs[128 * 32];

    const int t    = threadIdx.x;
    const int w    = t >> 6, lane = t & 63;
    const int m0   = blockIdx.y * 128, n0 = blockIdx.x * 128;
    const int l16  = lane & 15, quad = lane >> 4;
    const int wm   = (w & 1) * 64, wn = (w >> 1) * 64;

    const int c1 = w * 128 + lane;
    const int c2 = c1 + 64;
    const short* Ag1 = A + (size_t)(m0 + (c1 >> 2)) * K + (c1 & 3) * 8;
    const short* Ag2 = A + (size_t)(m0 + (c2 >> 2)) * K + (c2 & 3) * 8;
    const short* Bg1 = W + (size_t)(n0 + (c1 >> 2)) * K + (c1 & 3) * 8;
    const short* Bg2 = W + (size_t)(n0 + (c2 >> 2)) * K + (c2 & 3) * 8;
    short* Al = As + w * 1024;
    short* Bl = Bs + w * 1024;

    f32x4 acc[4][4] = {};
    const bool tv = TRANSV && (z == 2);

    for (int k0 = 0; k0 < K; k0 += 32) {
        GLOAD_LDS16(Ag1, Al);
        GLOAD_LDS16(Ag2, Al + 512);
        GLOAD_LDS16(Bg1, Bl);
        GLOAD_LDS16(Bg2, Bl + 512);
        Ag1 += 32; Ag2 += 32; Bg1 += 32; Bg2 += 32;
        __syncthreads();

        short8 af[4], bf[4];
        #pragma unroll
        for (int mi = 0; mi < 4; ++mi)
            af[mi] = *(const short8*)(As + (wm + mi * 16 + l16) * 32 + quad * 8);
        #pragma unroll
        for (int ni = 0; ni < 4; ++ni)
            bf[ni] = *(const short8*)(Bs + (wn + ni * 16 + l16) * 32 + quad * 8);
        if (tv) {
            #pragma unroll
            for (int mi = 0; mi < 4; ++mi)
                #pragma unroll
                for (int ni = 0; ni < 4; ++ni)
                    acc[mi][ni] = __builtin_amdgcn_mfma_f32_16x16x32_bf16(
                        bf[ni], af[mi], acc[mi][ni], 0, 0, 0);
        } else {
            #pragma unroll
            for (int mi = 0; mi < 4; ++mi)
                #pragma unroll
                for (int ni = 0; ni < 4; ++ni)
                    acc[mi][ni] = __builtin_amdgcn_mfma_f32_16x16x32_bf16(
                        af[mi], bf[ni], acc[mi][ni], 0, 0, 0);
        }
        __syncthreads();
    }

    if (tv) {
        // D[m=W-row][n=token]: write C^T [N][M]
        #pragma unroll
        for (int ni = 0; ni < 4; ++ni) {
            #pragma unroll
            for (int r = 0; r < 4; ++r) {
                const int wrow = n0 + wn + ni * 16 + quad * 4 + r;
                const float bb = bia[wrow];
                #pragma unroll
                for (int mi = 0; mi < 4; ++mi) {
                    const int tok = m0 + wm + mi * 16 + l16;
                    C[(size_t)wrow * M + tok] = __float2bfloat16(acc[mi][ni][r] + bb);
                }
            }
        }
    } else {
        #pragma unroll
        for (int ni = 0; ni < 4; ++ni) {
            const int col = n0 + wn + ni * 16 + l16;
            const float bb = bia[col];
            #pragma unroll
            for (int mi = 0; mi < 4; ++mi) {
                #pragma unroll
                for (int r = 0; r < 4; ++r) {
                    const int row = m0 + wm + mi * 16 + quad * 4 + r;
                    float v = acc[mi][ni][r] + bb;
                    if (RESID) v += __bfloat162float(R[(size_t)row * N + col]);
                    if (RELU)  v = fmaxf(v, 0.f);
                    C[(size_t)row * N + col] = __float2bfloat16(v);
                }
            }
        }
    }
}

// ---------------------------------------------------------------------------
// MFMA attention. q,k in [B,S,H*DK]; vT in [H*DK][B*S]; out in [B,S,H*DK].
// Block = (b,h,64-query tile), 4 waves x (16q x 256k).
// ---------------------------------------------------------------------------
__global__ __launch_bounds__(256)
void k_attn_mfma(const bf16* __restrict__ q, const bf16* __restrict__ k,
                 const bf16* __restrict__ vT, bf16* __restrict__ ocat)
{
    __shared__ __align__(16) short smem[33280];      // 66560 B
    short* Vst = smem;            // [64 dv][256 key], 16B chunks XOR-swizzled
    short* Ks  = smem + 16384;    // [256 key][64 dk], 16B chunks XOR-swizzled
    short* Ps  = smem + 16384;    // [64 q][264] bf16, overlays Ks (after barrier)

    const int t = threadIdx.x, w = t >> 6, lane = t & 63;
    const int l16 = lane & 15, quad = lane >> 4;
    const int qt = blockIdx.x & 3;
    const int h  = (blockIdx.x >> 2) & 7;
    const int b  = blockIdx.x >> 5;
    const int q0 = qt * 64;

    const short* kg = (const short*)k  + (size_t)b * Sn * Dn + h * DKn;
    const short* qg = (const short*)q  + (size_t)b * Sn * Dn + h * DKn;
    const short* vg = (const short*)vT + (size_t)h * DKn * BSn + b * Sn;

    #pragma unroll
    for (int i = 0; i < 8; ++i) {
        const int c   = w * 512 + i * 64 + lane;
        const int key = c >> 3, cgk = (c & 7) ^ (key & 7);
        GLOAD_LDS16(kg + (size_t)key * Dn + cgk * 8, Ks + (w * 512 + i * 64) * 8);
        const int dv = c >> 5, cgv = (c & 31) ^ (dv & 7);
        GLOAD_LDS16(vg + (size_t)dv * BSn + cgv * 8, Vst + (w * 512 + i * 64) * 8);
    }

    const short* qp = qg + (size_t)(q0 + w * 16 + l16) * Dn + quad * 8;
    short8 bq0 = *(const short8*)(qp);
    short8 bq1 = *(const short8*)(qp + 32);
    __syncthreads();

    // ---- S^T = K @ Q^T ----
    f32x4 accs[16];
    #pragma unroll
    for (int mi = 0; mi < 16; ++mi) accs[mi] = f32x4{0.f, 0.f, 0.f, 0.f};
    #pragma unroll
    for (int mi = 0; mi < 16; ++mi) {
        const int key = mi * 16 + l16;
        const int r0s = (quad     ^ (key & 7)) * 8;
        const int r1s = ((quad+4) ^ (key & 7)) * 8;
        short8 af0 = *(const short8*)(Ks + key * 64 + r0s);
        short8 af1 = *(const short8*)(Ks + key * 64 + r1s);
        accs[mi] = __builtin_amdgcn_mfma_f32_16x16x32_bf16(af0, bq0, accs[mi], 0, 0, 0);
        accs[mi] = __builtin_amdgcn_mfma_f32_16x16x32_bf16(af1, bq1, accs[mi], 0, 0, 0);
    }

    // ---- softmax over keys ----
    float mx = -1e30f;
    #pragma unroll
    for (int mi = 0; mi < 16; ++mi)
        #pragma unroll
        for (int r = 0; r < 4; ++r) mx = fmaxf(mx, accs[mi][r]);
    mx = fmaxf(mx, __shfl_xor(mx, 16));
    mx = fmaxf(mx, __shfl_xor(mx, 32));
    float sum = 0.f;
    #pragma unroll
    for (int mi = 0; mi < 16; ++mi)
        #pragma unroll
        for (int r = 0; r < 4; ++r) {
            float e = __expf((accs[mi][r] - mx) * 0.125f);
            accs[mi][r] = e;
            sum += e;
        }
    sum += __shfl_xor(sum, 16);
    sum += __shfl_xor(sum, 32);
    const float rs = 1.f / sum;

    __syncthreads();

    short* pr = Ps + (w * 16 + l16) * 264;
    #pragma unroll
    for (int mi = 0; mi < 16; ++mi) {
        short4v pk;
        pk.x = f2bs(accs[mi][0] * rs);
        pk.y = f2bs(accs[mi][1] * rs);
        pk.z = f2bs(accs[mi][2] * rs);
        pk.w = f2bs(accs[mi][3] * rs);
        *(short4v*)(pr + mi * 16 + quad * 4) = pk;
    }
    __syncthreads();

    // ---- O = P @ V ----
    f32x4 acco[4];
    #pragma unroll
    for (int nt = 0; nt < 4; ++nt) acco[nt] = f32x4{0.f, 0.f, 0.f, 0.f};
    #pragma unroll
    for (int k0 = 0; k0 < 8; ++k0) {
        short8 pa = *(const short8*)(pr + k0 * 32 + quad * 8);
        #pragma unroll
        for (int nt = 0; nt < 4; ++nt) {
            const int dv = nt * 16 + l16;
            const int sl = ((4 * k0 + quad) ^ (dv & 7)) * 8;
            short8 vb = *(const short8*)(Vst + dv * 256 + sl);
            acco[nt] = __builtin_amdgcn_mfma_f32_16x16x32_bf16(pa, vb, acco[nt], 0, 0, 0);
        }
    }

    #pragma unroll
    for (int nt = 0; nt < 4; ++nt) {
        #pragma unroll
        for (int r = 0; r < 4; ++r) {
            const int row = b * Sn + q0 + w * 16 + quad * 4 + r;
            const int col = h * DKn + nt * 16 + l16;
            ocat[(size_t)row * Dn + col] = __float2bfloat16(acco[nt][r]);
        }
    }
}

// ---------------------------------------------------------------------------
// LayerNorm over D=512: one wave per row, b128 loads, shfl-only reduction.
// Block = 4 waves = 4 rows. In-place safe (same thread RMW).
// ---------------------------------------------------------------------------
__global__ __launch_bounds__(256)
void k_ln(const bf16* __restrict__ y, const float* __restrict__ g,
          const float* __restrict__ be, bf16* __restrict__ xo)
{
    const int t = threadIdx.x, w = t >> 6, lane = t & 63;
    const int row = blockIdx.x * 4 + w;
    const short* yr = (const short*)y + (size_t)row * Dn + lane * 8;
    short8 v8 = *(const short8*)yr;
    float f[8];
    float s1 = 0.f, s2 = 0.f;
    #pragma unroll
    for (int i = 0; i < 8; ++i) {
        f[i] = bs2f(v8[i]);
        s1 += f[i];
        s2 += f[i] * f[i];
    }
    #pragma unroll
    for (int off = 1; off < 64; off <<= 1) {
        s1 += __shfl_xor(s1, off);
        s2 += __shfl_xor(s2, off);
    }
    const float mean = s1 * (1.f / Dn);
    const float var  = s2 * (1.f / Dn) - mean * mean;
    const float isd  = rsqrtf(var + 1e-5f);
    const float4 g0 = *(const float4*)(g  + lane * 8);
    const float4 g1 = *(const float4*)(g  + lane * 8 + 4);
    const float4 b0 = *(const float4*)(be + lane * 8);
    const float4 b1 = *(const float4*)(be + lane * 8 + 4);
    const float gg[8] = {g0.x, g0.y, g0.z, g0.w, g1.x, g1.y, g1.z, g1.w};
    const float bb[8] = {b0.x, b0.y, b0.z, b0.w, b1.x, b1.y, b1.z, b1.w};
    short8 o8;
    #pragma unroll
    for (int i = 0; i < 8; ++i)
        o8[i] = f2bs((f[i] - mean) * isd * gg[i] + bb[i]);
    *(short8*)((short*)xo + (size_t)row * Dn + lane * 8) = o8;
}

// ---------------------------------------------------------------------------
// Final head as skinny MFMA GEMM: out = sigmoid(X @ Wcat^T + bcat), 2 n-tiles
// (cols 0..8 -> output, 9..17 -> mask, 18..31 pad). Also writes float(time).
// Block = 4 waves x 16 rows = 64 rows. Grid 128. No LDS.
// ---------------------------------------------------------------------------
__global__ __launch_bounds__(256)
void k_final2(const bf16* __restrict__ x, const bf16* __restrict__ Wcat,
              const float* __restrict__ bcat, const int* __restrict__ timei,
              float* __restrict__ out)
{
    const int t = threadIdx.x, w = t >> 6, lane = t & 63;
    const int l16 = lane & 15, quad = lane >> 4;
    const int r0 = blockIdx.x * 64 + w * 16;
    const short* xp = (const short*)x + (size_t)(r0 + l16) * Dn + quad * 8;
    const short* wp = (const short*)Wcat + (size_t)l16 * Dn + quad * 8;

    f32x4 acc[2] = {};
    #pragma unroll
    for (int kk = 0; kk < 16; ++kk) {
        short8 af = *(const short8*)(xp + kk * 32);
        short8 b0 = *(const short8*)(wp + kk * 32);
        short8 b1 = *(const short8*)(wp + 16 * Dn + kk * 32);
        acc[0] = __builtin_amdgcn_mfma_f32_16x16x32_bf16(af, b0, acc[0], 0, 0, 0);
        acc[1] = __builtin_amdgcn_mfma_f32_16x16x32_bf16(af, b1, acc[1], 0, 0, 0);
    }

    #pragma unroll
    for (int nt = 0; nt < 2; ++nt) {
        const int col = nt * 16 + l16;
        const float bb = bcat[col];
        #pragma unroll
        for (int r = 0; r < 4; ++r) {
            const int row = r0 + quad * 4 + r;
            float v = acc[nt][r] + bb;
            float sg = 1.f / (1.f + expf(-v));
            if (col < FEATn)
                out[(size_t)row * FEATn + col] = sg;
            else if (col < 2 * FEATn)
                out[(size_t)BSn * FEATn + BSn + (size_t)row * FEATn + (col - FEATn)] = sg;
        }
    }
    if (l16 == 0) {
        #pragma unroll
        for (int r = 0; r < 4; ++r) {
            const int row = r0 + quad * 4 + r;
            out[(size_t)BSn * FEATn + row] = (float)timei[row];
        }
    }
}

// ---------------------------------------------------------------------------
extern "C" void kernel_launch(void* const* d_in, const int* in_sizes, int n_in,
                              void* d_out, int out_size, void* d_ws, size_t ws_size,
                              hipStream_t stream)
{
    const float* tgt    = (const float*)d_in[0];
    const float* memory = (const float*)d_in[1];
    const int*   timei  = (const int*)  d_in[2];
    const int*   gender = (const int*)  d_in[3];
    const int*   race   = (const int*)  d_in[4];
    const float* maskp  = (const float*)d_in[5];
    const float* w_f2h  = (const float*)d_in[6];
    const float* b_f2h  = (const float*)d_in[7];
    const float* emb_t  = (const float*)d_in[8];
    const float* emb_g  = (const float*)d_in[9];
    const float* emb_r  = (const float*)d_in[10];
    const float* wq1 = (const float*)d_in[11]; const float* bq1 = (const float*)d_in[12];
    const float* wk1 = (const float*)d_in[13]; const float* bk1 = (const float*)d_in[14];
    const float* wv1 = (const float*)d_in[15]; const float* bv1 = (const float*)d_in[16];
    const float* wo1 = (const float*)d_in[17]; const float* bo1 = (const float*)d_in[18];
    const float* g1  = (const float*)d_in[19]; const float* be1 = (const float*)d_in[20];
    const float* wq2 = (const float*)d_in[21]; const float* bq2 = (const float*)d_in[22];
    const float* wk2 = (const float*)d_in[23]; const float* bk2 = (const float*)d_in[24];
    const float* wv2 = (const float*)d_in[25]; const float* bv2 = (const float*)d_in[26];
    const float* wo2 = (const float*)d_in[27]; const float* bo2 = (const float*)d_in[28];
    const float* g2  = (const float*)d_in[29]; const float* be2 = (const float*)d_in[30];
    const float* w1f = (const float*)d_in[31]; const float* b1f = (const float*)d_in[32];
    const float* w2f = (const float*)d_in[33]; const float* b2f = (const float*)d_in[34];
    const float* gfp = (const float*)d_in[35]; const float* bff = (const float*)d_in[36];
    const float* w_out = (const float*)d_in[37]; const float* b_out = (const float*)d_in[38];
    const float* w_m   = (const float*)d_in[39]; const float* b_m   = (const float*)d_in[40];
    float* out = (float*)d_out;

    // ---- workspace layout (bf16 elems) ----
    constexpr size_t WH  = 1572864;            // headed / wo per-array
    constexpr size_t WF  = 6291456;            // w1f / w2f per-array
    constexpr size_t NA  = (size_t)BSn * Dn;   // activation elems
    bf16* wsb   = (bf16*)d_ws;
    bf16* wq1t  = wsb;
    bf16* wk1t  = wq1t + WH;
    bf16* wv1t  = wk1t + WH;
    bf16* wo1t  = wv1t + WH;
    bf16* wq2t  = wo1t + WH;
    bf16* wk2t  = wq2t + WH;
    bf16* wv2t  = wk2t + WH;
    bf16* wo2t  = wv2t + WH;
    bf16* w1ft  = wo2t + WH;
    bf16* w2ft  = w1ft + WF;
    bf16* memb  = w2ft + WF;
    bf16* x     = memb + NA;
    bf16* b1    = x  + NA;
    bf16* b2    = b1 + NA;
    bf16* b3    = b2 + NA;     // Vt [512][8192] from TRANSV v-proj
    bf16* b4    = b3 + NA;
    bf16* h1    = b1;          // [8192][2048] spans b1..b4
    bf16* wcat  = b4 + NA;     // [32][512]
    float* bcat = (float*)(wcat + 32 * Dn);

    dim3 blk(256);

    // ---- weight transpose+convert (batched) ----
    k_tcvt6<<<dim3( 2, 16, 288), blk, 0, stream>>>(
        wq1, wq1t, wk1, wk1t, wv1, wv1t, wq2, wq2t, wk2, wk2t, wv2, wv2t,
        512, 64, 48);
    k_tcvt6<<<dim3(16, 16, 12), blk, 0, stream>>>(
        wo1, wo1t, wo2, wo2t, wo1, wo1t, wo1, wo1t, wo1, wo1t, wo1, wo1t,
        512, 512, 6);
    k_tcvt6<<<dim3(64, 16, 6), blk, 0, stream>>>(
        w1f, w1ft, w1f, w1ft, w1f, w1ft, w1f, w1ft, w1f, w1ft, w1f, w1ft,
        512, 2048, 6);
    k_tcvt6<<<dim3(16, 64, 6), blk, 0, stream>>>(
        w2f, w2ft, w2f, w2ft, w2f, w2ft, w2f, w2ft, w2f, w2ft, w2f, w2ft,
        2048, 512, 6);
    k_cvt <<<dim3(NA / 256), blk, 0, stream>>>(memory, memb);
    k_prep_final<<<dim3(64), blk, 0, stream>>>(w_out, b_out, w_m, b_m, wcat, bcat);

    k_embed<<<dim3((BSn * Dn) / 256), blk, 0, stream>>>(
        tgt, maskp, w_f2h, b_f2h, timei, gender, race, emb_t, emb_g, emb_r, x);

    dim3 gP (Dn / 128, BSn / 128, 1);
    dim3 gP3(Dn / 128, BSn / 128, 3);
    dim3 gF (Fn / 128, BSn / 128, 1);
    dim3 gA (Bn * Hn * 4);
    dim3 gL (BSn / 4);
    constexpr size_t WSL = 262144;
    constexpr size_t WFL = 1048576;

    for (int l = 0; l < Ln; ++l) {
        // ---- self-attention ----
        k_gemm_bf<false, false, true><<<gP3, blk, 0, stream>>>(
            x, x, x,
            wq1t + l * WSL, wk1t + l * WSL, wv1t + l * WSL,
            bq1 + l * Dn, bk1 + l * Dn, bv1 + l * Dn,
            nullptr, b1, b2, b3, BSn, Dn, Dn);
        k_attn_mfma<<<gA, blk, 0, stream>>>(b1, b2, b3, b4);
        k_gemm_bf<false, true ><<<gP, blk, 0, stream>>>(
            b4, b4, b4, wo1t + l * WSL, wo1t + l * WSL, wo1t + l * WSL,
            bo1 + l * Dn, bo1 + l * Dn, bo1 + l * Dn,
            x, x, x, x, BSn, Dn, Dn);
        k_ln<<<gL, blk, 0, stream>>>(x, g1 + l * Dn, be1 + l * Dn, x);
        // ---- cross block: q,k from memory; v from x ----
        k_gemm_bf<false, false, true><<<gP3, blk, 0, stream>>>(
            memb, memb, x,
            wq2t + l * WSL, wk2t + l * WSL, wv2t + l * WSL,
            bq2 + l * Dn, bk2 + l * Dn, bv2 + l * Dn,
            nullptr, b1, b2, b3, BSn, Dn, Dn);
        k_attn_mfma<<<gA, blk, 0, stream>>>(b1, b2, b3, b4);
        k_gemm_bf<false, true ><<<gP, blk, 0, stream>>>(
            b4, b4, b4, wo2t + l * WSL, wo2t + l * WSL, wo2t + l * WSL,
            bo2 + l * Dn, bo2 + l * Dn, bo2 + l * Dn,
            x, x, x, x, BSn, Dn, Dn);
        k_ln<<<gL, blk, 0, stream>>>(x, g2 + l * Dn, be2 + l * Dn, x);
        // ---- feed-forward ----
        k_gemm_bf<true , false><<<gF, blk, 0, stream>>>(
            x, x, x, w1ft + l * WFL, w1ft + l * WFL, w1ft + l * WFL,
            b1f + l * Fn, b1f + l * Fn, b1f + l * Fn,
            nullptr, h1, h1, h1, BSn, Fn, Dn);
        k_gemm_bf<false, true ><<<gP, blk, 0, stream>>>(
            h1, h1, h1, w2ft + l * WFL, w2ft + l * WFL, w2ft + l * WFL,
            b2f + l * Dn, b2f + l * Dn, b2f + l * Dn,
            x, x, x, x, BSn, Dn, Fn);
        k_ln<<<gL, blk, 0, stream>>>(x, gfp + l * Dn, bff + l * Dn, x);
    }

    k_final2<<<dim3(BSn / 64), blk, 0, stream>>>(x, wcat, bcat, timei, out);
}

// Round 5
// 1690.109 us; speedup vs baseline: 5.1946x; 1.0321x over previous
//
#include <hip/hip_runtime.h>
#include <hip/hip_bf16.h>
#include <math.h>

// Problem constants
constexpr int Bn   = 32;
constexpr int Sn   = 256;
constexpr int Dn   = 512;
constexpr int Hn   = 8;
constexpr int DKn  = 64;
constexpr int Fn   = 2048;
constexpr int Ln   = 6;
constexpr int FEATn= 9;
constexpr int BSn  = Bn * Sn;          // 8192 rows

typedef __hip_bfloat16 bf16;
typedef __attribute__((ext_vector_type(8))) short short8;
typedef __attribute__((ext_vector_type(4))) short short4v;
typedef __attribute__((ext_vector_type(4))) float f32x4;

// global->LDS async copy, 16B per lane, LDS dest = wave-uniform base + lane*16
#define GLOAD_LDS16(gp, lp)                                                   \
    __builtin_amdgcn_global_load_lds(                                         \
        (const __attribute__((address_space(1))) void*)(gp),                  \
        (__attribute__((address_space(3))) void*)(lp), 16, 0, 0)

__device__ __forceinline__ short f2bs(float f) {
    __hip_bfloat16 h = __float2bfloat16(f);
    return *reinterpret_cast<short*>(&h);
}
__device__ __forceinline__ float bs2f(short s) {
    unsigned u = ((unsigned)(unsigned short)s) << 16;
    return *reinterpret_cast<float*>(&u);
}

// ---------------------------------------------------------------------------
// Embedding: x = (tgt*mask)@w_f2h + b_f2h + pos_emb + emb_time/gender/race
// ---------------------------------------------------------------------------
__global__ __launch_bounds__(256)
void k_embed(const float* __restrict__ tgt, const float* __restrict__ mask,
             const float* __restrict__ w_f2h, const float* __restrict__ b_f2h,
             const int* __restrict__ timei, const int* __restrict__ gender,
             const int* __restrict__ race,
             const float* __restrict__ emb_t, const float* __restrict__ emb_g,
             const float* __restrict__ emb_r, bf16* __restrict__ x)
{
    int idx = blockIdx.x * 256 + threadIdx.x;   // over BSn*Dn
    int d  = idx & (Dn - 1);
    int bs = idx >> 9;                           // /Dn
    int b  = bs / Sn;
    int s  = bs & (Sn - 1);
    const float* tg = tgt  + (size_t)bs * FEATn;
    const float* mk = mask + (size_t)bs * FEATn;
    float acc = b_f2h[d];
    #pragma unroll
    for (int f = 0; f < FEATn; ++f) acc += tg[f] * mk[f] * w_f2h[f * Dn + d];
    float phase = (float)s * expf(-((float)d / (float)Dn) * 9.210340372f); // ln(1e4)
    acc += (d & 1) ? cosf(phase) : sinf(phase);
    acc += emb_t[(size_t)timei[bs] * Dn + d];
    acc += emb_g[(size_t)gender[b] * Dn + d];
    acc += emb_r[(size_t)race[b]   * Dn + d];
    x[idx] = __float2bfloat16(acc);
}

// ---------------------------------------------------------------------------
// fp32 -> bf16 elementwise convert
// ---------------------------------------------------------------------------
__global__ __launch_bounds__(256)
void k_cvt(const float* __restrict__ in, bf16* __restrict__ out)
{
    int i = blockIdx.x * 256 + threadIdx.x;
    out[i] = __float2bfloat16(in[i]);
}

// ---------------------------------------------------------------------------
// Transpose + convert: in fp32 [B][R][C] -> out bf16 [B][C][R]
// Batched over up to 6 source/dest pairs: z in [0, 6*ZB); sel = z / ZB.
// ---------------------------------------------------------------------------
__global__ __launch_bounds__(256)
void k_tcvt6(const float* __restrict__ i0, bf16* __restrict__ o0,
             const float* __restrict__ i1, bf16* __restrict__ o1,
             const float* __restrict__ i2, bf16* __restrict__ o2,
             const float* __restrict__ i3, bf16* __restrict__ o3,
             const float* __restrict__ i4, bf16* __restrict__ o4,
             const float* __restrict__ i5, bf16* __restrict__ o5,
             int R, int C, int ZB)
{
    __shared__ float ts[32][33];
    const int sel = blockIdx.z / ZB, zi = blockIdx.z % ZB;
    const float* in  = sel == 0 ? i0 : sel == 1 ? i1 : sel == 2 ? i2
                     : sel == 3 ? i3 : sel == 4 ? i4 : i5;
    bf16*        out = sel == 0 ? o0 : sel == 1 ? o1 : sel == 2 ? o2
                     : sel == 3 ? o3 : sel == 4 ? o4 : o5;
    const int t  = threadIdx.x;
    const int tx = t & 31, ty = t >> 5;       // 8 rows per pass
    const int r0 = blockIdx.y * 32, c0 = blockIdx.x * 32;
    const size_t zo = (size_t)zi * R * C;
    #pragma unroll
    for (int i = 0; i < 4; ++i)
        ts[ty + 8 * i][tx] = in[zo + (size_t)(r0 + ty + 8 * i) * C + c0 + tx];
    __syncthreads();
    #pragma unroll
    for (int i = 0; i < 4; ++i)
        out[zo + (size_t)(c0 + ty + 8 * i) * R + r0 + tx] =
            __float2bfloat16(ts[tx][ty + 8 * i]);
}

// ---------------------------------------------------------------------------
// Prep for k_final2: Wcat bf16 [32][512] = concat(w_out^T, w_m^T, zero-pad),
// bcat fp32 [32] = concat(b_out, b_m, 0)
// ---------------------------------------------------------------------------
__global__ __launch_bounds__(256)
void k_prep_final(const float* __restrict__ w_out, const float* __restrict__ b_out,
                  const float* __restrict__ w_m, const float* __restrict__ b_m,
                  bf16* __restrict__ Wcat, float* __restrict__ bcat)
{
    int idx = blockIdx.x * 256 + threadIdx.x;   // 32*512
    int n = idx >> 9, k = idx & 511;
    float v = 0.f;
    if (n < FEATn)          v = w_out[(size_t)k * FEATn + n];
    else if (n < 2 * FEATn) v = w_m[(size_t)k * FEATn + (n - FEATn)];
    Wcat[idx] = __float2bfloat16(v);
    if (idx < 32) {
        float bv = idx < FEATn ? b_out[idx]
                 : (idx < 2 * FEATn ? b_m[idx - FEATn] : 0.f);
        bcat[idx] = bv;
    }
}

// ---------------------------------------------------------------------------
// bf16 MFMA GEMM: C[M,N] = A[M,K] @ Bt[N,K]^T + bias (+R)(ReLU)
// Tile BM x BN (template), BK=32, 4 waves in 2x2 grid, wave (BM/2)x(BN/2).
// blockIdx.z picks (A,W,bias,C).  TRANSV && z==2: operand-swapped MFMA ->
// writes C^T as [N][M] (for attention V).
// Tile choice = occupancy lever: 128x128 -> 256 blocks @ M=8192,N=512 (1/CU,
// barrier drain exposed); 64x64 -> 1024 blocks (4/CU, drain hidden by other
// blocks' waves).
// ---------------------------------------------------------------------------
template<int BM, int BN, bool RELU, bool RESID, bool TRANSV = false>
__global__ __launch_bounds__(256)
void k_gemm_bf(const bf16* __restrict__ A0, const bf16* __restrict__ A1,
               const bf16* __restrict__ A2,
               const bf16* __restrict__ W0, const bf16* __restrict__ W1,
               const bf16* __restrict__ W2,
               const float* __restrict__ bi0, const float* __restrict__ bi1,
               const float* __restrict__ bi2,
               const bf16* __restrict__ R,
               bf16* __restrict__ C0, bf16* __restrict__ C1, bf16* __restrict__ C2,
               int M, int N, int K)
{
    constexpr int WTM = BM / 2, WTN = BN / 2;     // wave tile
    constexpr int MT  = WTM / 16, NT = WTN / 16;  // MFMA tiles per wave
    constexpr int NCA = BM / 64;                  // A staging calls per wave
    constexpr int NCB = BN / 64;

    const int z = blockIdx.z;
    const short* A   = (const short*)(z == 0 ? A0 : (z == 1 ? A1 : A2));
    const short* W   = (const short*)(z == 0 ? W0 : (z == 1 ? W1 : W2));
    const float* bia = (z == 0 ? bi0 : (z == 1 ? bi1 : bi2));
    bf16*        C   = (z == 0 ? C0 : (z == 1 ? C1 : C2));

    __shared__ __align__(16) short As[BM * 32];   // [row][k] 64B rows
    __shared__ __align__(16) short Bs[BN * 32];

    const int t    = threadIdx.x;
    const int w    = t >> 6, lane = t & 63;
    const int m0   = blockIdx.y * BM, n0 = blockIdx.x * BN;
    const int l16  = lane & 15, quad = lane >> 4;
    const int wm   = (w & 1) * WTM, wn = (w >> 1) * WTN;

    // staging: chunk c (16B) covers row c>>2, k-part (c&3)*8; wave w owns
    // chunks [w*BM, (w+1)*BM) of A (resp. BN of B), 64 chunks per call.
    const short* Agp[NCA];
    const short* Bgp[NCB];
    #pragma unroll
    for (int i = 0; i < NCA; ++i) {
        const int c = w * BM + i * 64 + lane;
        Agp[i] = A + (size_t)(m0 + (c >> 2)) * K + (c & 3) * 8;
    }
    #pragma unroll
    for (int i = 0; i < NCB; ++i) {
        const int c = w * BN + i * 64 + lane;
        Bgp[i] = W + (size_t)(n0 + (c >> 2)) * K + (c & 3) * 8;
    }

    f32x4 acc[MT][NT] = {};
    const bool tv = TRANSV && (z == 2);

    for (int k0 = 0; k0 < K; k0 += 32) {
        #pragma unroll
        for (int i = 0; i < NCA; ++i) {
            GLOAD_LDS16(Agp[i], As + (w * BM + i * 64) * 8);
            Agp[i] += 32;
        }
        #pragma unroll
        for (int i = 0; i < NCB; ++i) {
            GLOAD_LDS16(Bgp[i], Bs + (w * BN + i * 64) * 8);
            Bgp[i] += 32;
        }
        __syncthreads();

        short8 af[MT], bf[NT];
        #pragma unroll
        for (int mi = 0; mi < MT; ++mi)
            af[mi] = *(const short8*)(As + (wm + mi * 16 + l16) * 32 + quad * 8);
        #pragma unroll
        for (int ni = 0; ni < NT; ++ni)
            bf[ni] = *(const short8*)(Bs + (wn + ni * 16 + l16) * 32 + quad * 8);
        if (tv) {
            #pragma unroll
            for (int mi = 0; mi < MT; ++mi)
                #pragma unroll
                for (int ni = 0; ni < NT; ++ni)
                    acc[mi][ni] = __builtin_amdgcn_mfma_f32_16x16x32_bf16(
                        bf[ni], af[mi], acc[mi][ni], 0, 0, 0);
        } else {
            #pragma unroll
            for (int mi = 0; mi < MT; ++mi)
                #pragma unroll
                for (int ni = 0; ni < NT; ++ni)
                    acc[mi][ni] = __builtin_amdgcn_mfma_f32_16x16x32_bf16(
                        af[mi], bf[ni], acc[mi][ni], 0, 0, 0);
        }
        __syncthreads();
    }

    if (tv) {
        // D[m=W-row][n=token]: write C^T [N][M]
        #pragma unroll
        for (int ni = 0; ni < NT; ++ni) {
            #pragma unroll
            for (int r = 0; r < 4; ++r) {
                const int wrow = n0 + wn + ni * 16 + quad * 4 + r;
                const float bb = bia[wrow];
                #pragma unroll
                for (int mi = 0; mi < MT; ++mi) {
                    const int tok = m0 + wm + mi * 16 + l16;
                    C[(size_t)wrow * M + tok] = __float2bfloat16(acc[mi][ni][r] + bb);
                }
            }
        }
    } else {
        #pragma unroll
        for (int ni = 0; ni < NT; ++ni) {
            const int col = n0 + wn + ni * 16 + l16;
            const float bb = bia[col];
            #pragma unroll
            for (int mi = 0; mi < MT; ++mi) {
                #pragma unroll
                for (int r = 0; r < 4; ++r) {
                    const int row = m0 + wm + mi * 16 + quad * 4 + r;
                    float v = acc[mi][ni][r] + bb;
                    if (RESID) v += __bfloat162float(R[(size_t)row * N + col]);
                    if (RELU)  v = fmaxf(v, 0.f);
                    C[(size_t)row * N + col] = __float2bfloat16(v);
                }
            }
        }
    }
}

// ---------------------------------------------------------------------------
// MFMA attention. q,k in [B,S,H*DK]; vT in [H*DK][B*S]; out in [B,S,H*DK].
// Block = (b,h,64-query tile), 4 waves x (16q x 256k).
// ---------------------------------------------------------------------------
__global__ __launch_bounds__(256)
void k_attn_mfma(const bf16* __restrict__ q, const bf16* __restrict__ k,
                 const bf16* __restrict__ vT, bf16* __restrict__ ocat)
{
    __shared__ __align__(16) short smem[33280];      // 66560 B
    short* Vst = smem;            // [64 dv][256 key], 16B chunks XOR-swizzled
    short* Ks  = smem + 16384;    // [256 key][64 dk], 16B chunks XOR-swizzled
    short* Ps  = smem + 16384;    // [64 q][264] bf16, overlays Ks (after barrier)

    const int t = threadIdx.x, w = t >> 6, lane = t & 63;
    const int l16 = lane & 15, quad = lane >> 4;
    const int qt = blockIdx.x & 3;
    const int h  = (blockIdx.x >> 2) & 7;
    const int b  = blockIdx.x >> 5;
    const int q0 = qt * 64;

    const short* kg = (const short*)k  + (size_t)b * Sn * Dn + h * DKn;
    const short* qg = (const short*)q  + (size_t)b * Sn * Dn + h * DKn;
    const short* vg = (const short*)vT + (size_t)h * DKn * BSn + b * Sn;

    #pragma unroll
    for (int i = 0; i < 8; ++i) {
        const int c   = w * 512 + i * 64 + lane;
        const int key = c >> 3, cgk = (c & 7) ^ (key & 7);
        GLOAD_LDS16(kg + (size_t)key * Dn + cgk * 8, Ks + (w * 512 + i * 64) * 8);
        const int dv = c >> 5, cgv = (c & 31) ^ (dv & 7);
        GLOAD_LDS16(vg + (size_t)dv * BSn + cgv * 8, Vst + (w * 512 + i * 64) * 8);
    }

    const short* qp = qg + (size_t)(q0 + w * 16 + l16) * Dn + quad * 8;
    short8 bq0 = *(const short8*)(qp);
    short8 bq1 = *(const short8*)(qp + 32);
    __syncthreads();

    // ---- S^T = K @ Q^T ----
    f32x4 accs[16];
    #pragma unroll
    for (int mi = 0; mi < 16; ++mi) accs[mi] = f32x4{0.f, 0.f, 0.f, 0.f};
    #pragma unroll
    for (int mi = 0; mi < 16; ++mi) {
        const int key = mi * 16 + l16;
        const int r0s = (quad     ^ (key & 7)) * 8;
        const int r1s = ((quad+4) ^ (key & 7)) * 8;
        short8 af0 = *(const short8*)(Ks + key * 64 + r0s);
        short8 af1 = *(const short8*)(Ks + key * 64 + r1s);
        accs[mi] = __builtin_amdgcn_mfma_f32_16x16x32_bf16(af0, bq0, accs[mi], 0, 0, 0);
        accs[mi] = __builtin_amdgcn_mfma_f32_16x16x32_bf16(af1, bq1, accs[mi], 0, 0, 0);
    }

    // ---- softmax over keys ----
    float mx = -1e30f;
    #pragma unroll
    for (int mi = 0; mi < 16; ++mi)
        #pragma unroll
        for (int r = 0; r < 4; ++r) mx = fmaxf(mx, accs[mi][r]);
    mx = fmaxf(mx, __shfl_xor(mx, 16));
    mx = fmaxf(mx, __shfl_xor(mx, 32));
    float sum = 0.f;
    #pragma unroll
    for (int mi = 0; mi < 16; ++mi)
        #pragma unroll
        for (int r = 0; r < 4; ++r) {
            float e = __expf((accs[mi][r] - mx) * 0.125f);
            accs[mi][r] = e;
            sum += e;
        }
    sum += __shfl_xor(sum, 16);
    sum += __shfl_xor(sum, 32);
    const float rs = 1.f / sum;

    __syncthreads();

    short* pr = Ps + (w * 16 + l16) * 264;
    #pragma unroll
    for (int mi = 0; mi < 16; ++mi) {
        short4v pk;
        pk.x = f2bs(accs[mi][0] * rs);
        pk.y = f2bs(accs[mi][1] * rs);
        pk.z = f2bs(accs[mi][2] * rs);
        pk.w = f2bs(accs[mi][3] * rs);
        *(short4v*)(pr + mi * 16 + quad * 4) = pk;
    }
    __syncthreads();

    // ---- O = P @ V ----
    f32x4 acco[4];
    #pragma unroll
    for (int nt = 0; nt < 4; ++nt) acco[nt] = f32x4{0.f, 0.f, 0.f, 0.f};
    #pragma unroll
    for (int k0 = 0; k0 < 8; ++k0) {
        short8 pa = *(const short8*)(pr + k0 * 32 + quad * 8);
        #pragma unroll
        for (int nt = 0; nt < 4; ++nt) {
            const int dv = nt * 16 + l16;
            const int sl = ((4 * k0 + quad) ^ (dv & 7)) * 8;
            short8 vb = *(const short8*)(Vst + dv * 256 + sl);
            acco[nt] = __builtin_amdgcn_mfma_f32_16x16x32_bf16(pa, vb, acco[nt], 0, 0, 0);
        }
    }

    #pragma unroll
    for (int nt = 0; nt < 4; ++nt) {
        #pragma unroll
        for (int r = 0; r < 4; ++r) {
            const int row = b * Sn + q0 + w * 16 + quad * 4 + r;
            const int col = h * DKn + nt * 16 + l16;
            ocat[(size_t)row * Dn + col] = __float2bfloat16(acco[nt][r]);
        }
    }
}

// ---------------------------------------------------------------------------
// LayerNorm over D=512: one wave per row, b128 loads, shfl-only reduction.
// ---------------------------------------------------------------------------
__global__ __launch_bounds__(256)
void k_ln(const bf16* __restrict__ y, const float* __restrict__ g,
          const float* __restrict__ be, bf16* __restrict__ xo)
{
    const int t = threadIdx.x, w = t >> 6, lane = t & 63;
    const int row = blockIdx.x * 4 + w;
    const short* yr = (const short*)y + (size_t)row * Dn + lane * 8;
    short8 v8 = *(const short8*)yr;
    float f[8];
    float s1 = 0.f, s2 = 0.f;
    #pragma unroll
    for (int i = 0; i < 8; ++i) {
        f[i] = bs2f(v8[i]);
        s1 += f[i];
        s2 += f[i] * f[i];
    }
    #pragma unroll
    for (int off = 1; off < 64; off <<= 1) {
        s1 += __shfl_xor(s1, off);
        s2 += __shfl_xor(s2, off);
    }
    const float mean = s1 * (1.f / Dn);
    const float var  = s2 * (1.f / Dn) - mean * mean;
    const float isd  = rsqrtf(var + 1e-5f);
    const float4 g0 = *(const float4*)(g  + lane * 8);
    const float4 g1 = *(const float4*)(g  + lane * 8 + 4);
    const float4 b0 = *(const float4*)(be + lane * 8);
    const float4 b1 = *(const float4*)(be + lane * 8 + 4);
    const float gg[8] = {g0.x, g0.y, g0.z, g0.w, g1.x, g1.y, g1.z, g1.w};
    const float bb[8] = {b0.x, b0.y, b0.z, b0.w, b1.x, b1.y, b1.z, b1.w};
    short8 o8;
    #pragma unroll
    for (int i = 0; i < 8; ++i)
        o8[i] = f2bs((f[i] - mean) * isd * gg[i] + bb[i]);
    *(short8*)((short*)xo + (size_t)row * Dn + lane * 8) = o8;
}

// ---------------------------------------------------------------------------
// Final head as skinny MFMA GEMM: out = sigmoid(X @ Wcat^T + bcat).
// ---------------------------------------------------------------------------
__global__ __launch_bounds__(256)
void k_final2(const bf16* __restrict__ x, const bf16* __restrict__ Wcat,
              const float* __restrict__ bcat, const int* __restrict__ timei,
              float* __restrict__ out)
{
    const int t = threadIdx.x, w = t >> 6, lane = t & 63;
    const int l16 = lane & 15, quad = lane >> 4;
    const int r0 = blockIdx.x * 64 + w * 16;
    const short* xp = (const short*)x + (size_t)(r0 + l16) * Dn + quad * 8;
    const short* wp = (const short*)Wcat + (size_t)l16 * Dn + quad * 8;

    f32x4 acc[2] = {};
    #pragma unroll
    for (int kk = 0; kk < 16; ++kk) {
        short8 af = *(const short8*)(xp + kk * 32);
        short8 b0 = *(const short8*)(wp + kk * 32);
        short8 b1 = *(const short8*)(wp + 16 * Dn + kk * 32);
        acc[0] = __builtin_amdgcn_mfma_f32_16x16x32_bf16(af, b0, acc[0], 0, 0, 0);
        acc[1] = __builtin_amdgcn_mfma_f32_16x16x32_bf16(af, b1, acc[1], 0, 0, 0);
    }

    #pragma unroll
    for (int nt = 0; nt < 2; ++nt) {
        const int col = nt * 16 + l16;
        const float bb = bcat[col];
        #pragma unroll
        for (int r = 0; r < 4; ++r) {
            const int row = r0 + quad * 4 + r;
            float v = acc[nt][r] + bb;
            float sg = 1.f / (1.f + expf(-v));
            if (col < FEATn)
                out[(size_t)row * FEATn + col] = sg;
            else if (col < 2 * FEATn)
                out[(size_t)BSn * FEATn + BSn + (size_t)row * FEATn + (col - FEATn)] = sg;
        }
    }
    if (l16 == 0) {
        #pragma unroll
        for (int r = 0; r < 4; ++r) {
            const int row = r0 + quad * 4 + r;
            out[(size_t)BSn * FEATn + row] = (float)timei[row];
        }
    }
}

// ---------------------------------------------------------------------------
extern "C" void kernel_launch(void* const* d_in, const int* in_sizes, int n_in,
                              void* d_out, int out_size, void* d_ws, size_t ws_size,
                              hipStream_t stream)
{
    const float* tgt    = (const float*)d_in[0];
    const float* memory = (const float*)d_in[1];
    const int*   timei  = (const int*)  d_in[2];
    const int*   gender = (const int*)  d_in[3];
    const int*   race   = (const int*)  d_in[4];
    const float* maskp  = (const float*)d_in[5];
    const float* w_f2h  = (const float*)d_in[6];
    const float* b_f2h  = (const float*)d_in[7];
    const float* emb_t  = (const float*)d_in[8];
    const float* emb_g  = (const float*)d_in[9];
    const float* emb_r  = (const float*)d_in[10];
    const float* wq1 = (const float*)d_in[11]; const float* bq1 = (const float*)d_in[12];
    const float* wk1 = (const float*)d_in[13]; const float* bk1 = (const float*)d_in[14];
    const float* wv1 = (const float*)d_in[15]; const float* bv1 = (const float*)d_in[16];
    const float* wo1 = (const float*)d_in[17]; const float* bo1 = (const float*)d_in[18];
    const float* g1  = (const float*)d_in[19]; const float* be1 = (const float*)d_in[20];
    const float* wq2 = (const float*)d_in[21]; const float* bq2 = (const float*)d_in[22];
    const float* wk2 = (const float*)d_in[23]; const float* bk2 = (const float*)d_in[24];
    const float* wv2 = (const float*)d_in[25]; const float* bv2 = (const float*)d_in[26];
    const float* wo2 = (const float*)d_in[27]; const float* bo2 = (const float*)d_in[28];
    const float* g2  = (const float*)d_in[29]; const float* be2 = (const float*)d_in[30];
    const float* w1f = (const float*)d_in[31]; const float* b1f = (const float*)d_in[32];
    const float* w2f = (const float*)d_in[33]; const float* b2f = (const float*)d_in[34];
    const float* gfp = (const float*)d_in[35]; const float* bff = (const float*)d_in[36];
    const float* w_out = (const float*)d_in[37]; const float* b_out = (const float*)d_in[38];
    const float* w_m   = (const float*)d_in[39]; const float* b_m   = (const float*)d_in[40];
    float* out = (float*)d_out;

    // ---- workspace layout (bf16 elems) ----
    constexpr size_t WH  = 1572864;            // headed / wo per-array
    constexpr size_t WF  = 6291456;            // w1f / w2f per-array
    constexpr size_t NA  = (size_t)BSn * Dn;   // activation elems
    bf16* wsb   = (bf16*)d_ws;
    bf16* wq1t  = wsb;
    bf16* wk1t  = wq1t + WH;
    bf16* wv1t  = wk1t + WH;
    bf16* wo1t  = wv1t + WH;
    bf16* wq2t  = wo1t + WH;
    bf16* wk2t  = wq2t + WH;
    bf16* wv2t  = wk2t + WH;
    bf16* wo2t  = wv2t + WH;
    bf16* w1ft  = wo2t + WH;
    bf16* w2ft  = w1ft + WF;
    bf16* memb  = w2ft + WF;
    bf16* x     = memb + NA;
    bf16* b1    = x  + NA;
    bf16* b2    = b1 + NA;
    bf16* b3    = b2 + NA;     // Vt [512][8192] from TRANSV v-proj
    bf16* b4    = b3 + NA;
    bf16* h1    = b1;          // [8192][2048] spans b1..b4
    bf16* wcat  = b4 + NA;     // [32][512]
    float* bcat = (float*)(wcat + 32 * Dn);

    dim3 blk(256);

    // ---- weight transpose+convert (batched) ----
    k_tcvt6<<<dim3( 2, 16, 288), blk, 0, stream>>>(
        wq1, wq1t, wk1, wk1t, wv1, wv1t, wq2, wq2t, wk2, wk2t, wv2, wv2t,
        512, 64, 48);
    k_tcvt6<<<dim3(16, 16, 12), blk, 0, stream>>>(
        wo1, wo1t, wo2, wo2t, wo1, wo1t, wo1, wo1t, wo1, wo1t, wo1, wo1t,
        512, 512, 6);
    k_tcvt6<<<dim3(64, 16, 6), blk, 0, stream>>>(
        w1f, w1ft, w1f, w1ft, w1f, w1ft, w1f, w1ft, w1f, w1ft, w1f, w1ft,
        512, 2048, 6);
    k_tcvt6<<<dim3(16, 64, 6), blk, 0, stream>>>(
        w2f, w2ft, w2f, w2ft, w2f, w2ft, w2f, w2ft, w2f, w2ft, w2f, w2ft,
        2048, 512, 6);
    k_cvt <<<dim3(NA / 256), blk, 0, stream>>>(memory, memb);
    k_prep_final<<<dim3(64), blk, 0, stream>>>(w_out, b_out, w_m, b_m, wcat, bcat);

    k_embed<<<dim3((BSn * Dn) / 256), blk, 0, stream>>>(
        tgt, maskp, w_f2h, b_f2h, timei, gender, race, emb_t, emb_g, emb_r, x);

    dim3 gP3(Dn / 128, BSn / 128, 3);   // qkv fused, 128x128: 768 blocks (3/CU)
    dim3 gP6(Dn / 64,  BSn / 64,  1);   // wo / ffn2, 64x64: 1024 blocks (4/CU)
    dim3 gF (Fn / 128, BSn / 128, 1);   // ffn1, 128x128: 1024 blocks (4/CU)
    dim3 gA (Bn * Hn * 4);
    dim3 gL (BSn / 4);
    constexpr size_t WSL = 262144;
    constexpr size_t WFL = 1048576;

    for (int l = 0; l < Ln; ++l) {
        // ---- self-attention ----
        k_gemm_bf<128, 128, false, false, true><<<gP3, blk, 0, stream>>>(
            x, x, x,
            wq1t + l * WSL, wk1t + l * WSL, wv1t + l * WSL,
            bq1 + l * Dn, bk1 + l * Dn, bv1 + l * Dn,
            nullptr, b1, b2, b3, BSn, Dn, Dn);
        k_attn_mfma<<<gA, blk, 0, stream>>>(b1, b2, b3, b4);
        k_gemm_bf<64, 64, false, true><<<gP6, blk, 0, stream>>>(
            b4, b4, b4, wo1t + l * WSL, wo1t + l * WSL, wo1t + l * WSL,
            bo1 + l * Dn, bo1 + l * Dn, bo1 + l * Dn,
            x, x, x, x, BSn, Dn, Dn);
        k_ln<<<gL, blk, 0, stream>>>(x, g1 + l * Dn, be1 + l * Dn, x);
        // ---- cross block: q,k from memory; v from x ----
        k_gemm_bf<128, 128, false, false, true><<<gP3, blk, 0, stream>>>(
            memb, memb, x,
            wq2t + l * WSL, wk2t + l * WSL, wv2t + l * WSL,
            bq2 + l * Dn, bk2 + l * Dn, bv2 + l * Dn,
            nullptr, b1, b2, b3, BSn, Dn, Dn);
        k_attn_mfma<<<gA, blk, 0, stream>>>(b1, b2, b3, b4);
        k_gemm_bf<64, 64, false, true><<<gP6, blk, 0, stream>>>(
            b4, b4, b4, wo2t + l * WSL, wo2t + l * WSL, wo2t + l * WSL,
            bo2 + l * Dn, bo2 + l * Dn, bo2 + l * Dn,
            x, x, x, x, BSn, Dn, Dn);
        k_ln<<<gL, blk, 0, stream>>>(x, g2 + l * Dn, be2 + l * Dn, x);
        // ---- feed-forward ----
        k_gemm_bf<128, 128, true, false><<<gF, blk, 0, stream>>>(
            x, x, x, w1ft + l * WFL, w1ft + l * WFL, w1ft + l * WFL,
            b1f + l * Fn, b1f + l * Fn, b1f + l * Fn,
            nullptr, h1, h1, h1, BSn, Fn, Dn);
        k_gemm_bf<64, 64, false, true><<<gP6, blk, 0, stream>>>(
            h1, h1, h1, w2ft + l * WFL, w2ft + l * WFL, w2ft + l * WFL,
            b2f + l * Dn, b2f + l * Dn, b2f + l * Dn,
            x, x, x, x, BSn, Dn, Fn);
        k_ln<<<gL, blk, 0, stream>>>(x, gfp + l * Dn, bff + l * Dn, x);
    }

    k_final2<<<dim3(BSn / 64), blk, 0, stream>>>(x, wcat, bcat, timei, out);
}